// Round 6
// baseline (3949.268 us; speedup 1.0000x reference)
//
#include <hip/hip_runtime.h>

typedef unsigned short u16;
typedef unsigned int u32;
typedef __attribute__((ext_vector_type(8))) short short8;   // 8 x bf16 (4 VGPRs)
typedef __attribute__((ext_vector_type(4))) float float4v;  // 4 x f32

#define DEV static __device__ __forceinline__

DEV float bf2f(u16 u) { u32 x = ((u32)u) << 16; float f; __builtin_memcpy(&f, &x, 4); return f; }
DEV u16 f2bf(float f) {
  u32 u; __builtin_memcpy(&u, &f, 4);
  u = (u + 0x7fffu + ((u >> 16) & 1u)) >> 16;
  return (u16)u;
}
DEV float sigm(float x) { return 1.f / (1.f + __expf(-x)); }

// async global->LDS, 16B per lane; LDS dest = wave-uniform base + lane*16
DEV void gl16(const u16* g, u16* l) {
  __builtin_amdgcn_global_load_lds(
      (const __attribute__((address_space(1))) void*)g,
      (__attribute__((address_space(3))) void*)l, 16, 0, 0);
}

// ============================================================
// Generic GEMM (small cases): C[M,N] = A[M,K](bf16) * B[N,K](bf16 "NK")
// OMODE: 0 = f32 row-major, 3 = f32 + bias + tanh-GELU epilogue (fc1)
// ============================================================
template <int OMODE>
__launch_bounds__(256)
__global__ void gemm_nt(const u16* __restrict__ A, int lda,
                        const u16* __restrict__ B, int ldb,
                        void* __restrict__ Cp, int ldc,
                        int M, int N, int K,
                        const float* __restrict__ bias)
{
  constexpr int PK = 40;
  __shared__ u16 As[128 * PK];
  __shared__ u16 Bs[64 * PK];

  const int tid  = threadIdx.x;
  const int m0   = blockIdx.y * 128;
  const int n0   = blockIdx.x * 64;
  const int wid  = tid >> 6;
  const int lane = tid & 63;
  const int l15  = lane & 15;
  const int quad = lane >> 4;
  const int wm   = (wid >> 1) * 64;
  const int wn   = (wid & 1) * 32;

  float4v acc[4][2];
  const float4v fz = {0.f, 0.f, 0.f, 0.f};
#pragma unroll
  for (int i = 0; i < 4; i++)
#pragma unroll
    for (int j = 0; j < 2; j++) acc[i][j] = fz;

  const int arow = tid >> 2;
  const int akc  = tid & 3;

  const int kt_count = (K + 31) / 32;
  for (int kt = 0; kt < kt_count; ++kt) {
    const int k0 = kt * 32 + akc * 8;
    const bool kok = (k0 < K);
    uint4 av0 = make_uint4(0, 0, 0, 0), av1 = av0, bv = av0;
    int ra = m0 + arow;
    if (kok && ra < M)        av0 = *(const uint4*)(A + (size_t)ra * lda + k0);
    if (kok && ra + 64 < M)   av1 = *(const uint4*)(A + (size_t)(ra + 64) * lda + k0);
    int rb = n0 + arow;
    if (kok && rb < N)        bv  = *(const uint4*)(B + (size_t)rb * ldb + k0);

    __syncthreads();
    *(uint4*)&As[arow * PK + akc * 8]        = av0;
    *(uint4*)&As[(arow + 64) * PK + akc * 8] = av1;
    *(uint4*)&Bs[arow * PK + akc * 8]        = bv;
    __syncthreads();

    short8 af[4], bfr[2];
#pragma unroll
    for (int i = 0; i < 4; i++)
      af[i] = *(const short8*)&As[(wm + i * 16 + l15) * PK + quad * 8];
#pragma unroll
    for (int j = 0; j < 2; j++)
      bfr[j] = *(const short8*)&Bs[(wn + j * 16 + l15) * PK + quad * 8];
#pragma unroll
    for (int i = 0; i < 4; i++)
#pragma unroll
      for (int j = 0; j < 2; j++)
        acc[i][j] = __builtin_amdgcn_mfma_f32_16x16x32_bf16(af[i], bfr[j], acc[i][j], 0, 0, 0);
  }

#pragma unroll
  for (int i = 0; i < 4; i++)
#pragma unroll
    for (int j = 0; j < 2; j++)
#pragma unroll
      for (int e = 0; e < 4; e++) {
        int r = m0 + wm + i * 16 + quad * 4 + e;
        int c = n0 + wn + j * 16 + l15;
        if (r < M && c < N) {
          float v = acc[i][j][e];
          if (OMODE == 0) ((float*)Cp)[(size_t)r * ldc + c] = v;
          else {
            float a = v + bias[c];
            float t = tanhf(0.7978845608028654f * (a + 0.044715f * a * a * a));
            ((float*)Cp)[(size_t)r * ldc + c] = 0.5f * a * (1.f + t);
          }
        }
      }
}

// ============================================================
// Big graph-conv GEMM: Gg = S(1000x1024) @ h2t(36864x1024)^T
// 128x128x32, global_load_lds(16B), XCD swizzle, g-layout scatter.
// ============================================================
__launch_bounds__(256)
__global__ void k_bigemm(const u16* __restrict__ A,
                         const u16* __restrict__ B,
                         u16* __restrict__ Gg)
{
  __shared__ u16 As[128 * 32];
  __shared__ u16 Bs[128 * 32];
  const int tid  = threadIdx.x;
  const int bid  = blockIdx.x;
  const int xcd  = bid & 7;
  const int jj   = bid >> 3;
  const int m0   = (jj & 7) * 128;
  const int n0   = (xcd + 8 * (jj >> 3)) * 128;

  const int wid  = tid >> 6;
  const int lane = tid & 63;
  const int l15  = lane & 15;
  const int quad = lane >> 4;
  const int wm   = (wid >> 1) * 64;
  const int wn   = (wid & 1) * 64;

  const int srow = wid * 16 + (lane >> 2);
  const int skc  = (lane & 3) * 8;

  const u16* agp0 = A + (size_t)(m0 + srow) * 1024 + skc;
  const u16* agp1 = agp0 + (size_t)64 * 1024;
  const u16* bgp0 = B + (size_t)(n0 + srow) * 1024 + skc;
  const u16* bgp1 = bgp0 + (size_t)64 * 1024;
  u16* asl0 = &As[(wid * 16) * 32];
  u16* asl1 = &As[(64 + wid * 16) * 32];
  u16* bsl0 = &Bs[(wid * 16) * 32];
  u16* bsl1 = &Bs[(64 + wid * 16) * 32];

  float4v acc[4][4];
  const float4v fz = {0.f, 0.f, 0.f, 0.f};
#pragma unroll
  for (int i = 0; i < 4; i++)
#pragma unroll
    for (int j = 0; j < 4; j++) acc[i][j] = fz;

  for (int kt = 0; kt < 32; ++kt) {
    const int ko = kt * 32;
    gl16(agp0 + ko, asl0);
    gl16(agp1 + ko, asl1);
    gl16(bgp0 + ko, bsl0);
    gl16(bgp1 + ko, bsl1);
    __syncthreads();
    short8 af[4], bf[4];
#pragma unroll
    for (int i = 0; i < 4; i++)
      af[i] = *(const short8*)&As[(wm + i * 16 + l15) * 32 + quad * 8];
#pragma unroll
    for (int j = 0; j < 4; j++)
      bf[j] = *(const short8*)&Bs[(wn + j * 16 + l15) * 32 + quad * 8];
#pragma unroll
    for (int i = 0; i < 4; i++)
#pragma unroll
      for (int j = 0; j < 4; j++)
        acc[i][j] = __builtin_amdgcn_mfma_f32_16x16x32_bf16(af[i], bf[j], acc[i][j], 0, 0, 0);
    __syncthreads();
  }

#pragma unroll
  for (int i = 0; i < 4; i++)
#pragma unroll
    for (int j = 0; j < 4; j++)
#pragma unroll
      for (int e = 0; e < 4; e++) {
        int r = m0 + wm + i * 16 + quad * 4 + e;
        if (r < 1000) {
          int c = n0 + wn + j * 16 + l15;
          int rs = c / 96, cc = c - rs * 96;
          Gg[(size_t)rs * 96000 + (size_t)r * 96 + cc] = f2bf(acc[i][j][e]);
        }
      }
}

// ============================================================
// Fused GRU step, full-row blocks: BM=64, all 576 outputs per block.
// POOL: in-block score reduction + online-softmax Nv/M/L update
// (recompute-pass keeps hnew out of long-lived registers).
// ============================================================
template <int KX, bool POOL>
__launch_bounds__(256)
__global__ void k_gru(const u16* __restrict__ Xin, int ldx,
                      const u16* __restrict__ Win,
                      const u16* __restrict__ Hin,
                      const u16* __restrict__ Whh,
                      const float* __restrict__ bih, const float* __restrict__ bhh,
                      u16* __restrict__ Hout,
                      const float* __restrict__ att_w,
                      float* __restrict__ Mbuf, float* __restrict__ Lbuf,
                      float* __restrict__ Nv, int t0)
{
  __shared__ u16 As[64 * 32];
  __shared__ u16 Bs[576 * 32];
  __shared__ float score_s[64][2];
  __shared__ float bc_s[64][2];

  const int tid  = threadIdx.x;
  const int m0   = blockIdx.x * 64;
  const int wid  = tid >> 6;
  const int lane = tid & 63;
  const int l15  = lane & 15;
  const int quad = lane >> 4;
  const int wm   = (wid >> 1) * 32;
  const int wn   = (wid & 1) * 96;
  const int lrow = lane >> 2;
  const int lkc  = (lane & 3) * 8;

  float4v aR[2][6], aZ[2][6], aN[2][6], aH[2][6];
  const float4v fz = {0.f, 0.f, 0.f, 0.f};
#pragma unroll
  for (int i = 0; i < 2; i++)
#pragma unroll
    for (int j = 0; j < 6; j++) { aR[i][j] = fz; aZ[i][j] = fz; aN[i][j] = fz; aH[i][j] = fz; }

  u16* asl = &As[(wid * 16) * 32];

  // ---- phase X: R/Z/N accs += X @ Win^T  (KX = 96 or 192) ----
  {
    const u16* ab = Xin + (size_t)(m0 + wid * 16 + lrow) * ldx + lkc;
    const u16* bb = Win + (size_t)(wid * 16 + lrow) * KX + lkc;
#pragma unroll
    for (int kt = 0; kt < KX / 32; ++kt) {
      const int ko = kt * 32;
      gl16(ab + ko, asl);
#pragma unroll
      for (int r = 0; r < 9; r++)
        gl16(bb + (size_t)(r * 64) * KX + ko, &Bs[(r * 64 + wid * 16) * 32]);
      __syncthreads();
      short8 af[2];
#pragma unroll
      for (int i = 0; i < 2; i++)
        af[i] = *(const short8*)&As[(wm + i * 16 + l15) * 32 + quad * 8];
#pragma unroll
      for (int j = 0; j < 6; j++) {
        short8 bR = *(const short8*)&Bs[(wn + j * 16 + l15) * 32 + quad * 8];
        short8 bZ = *(const short8*)&Bs[(192 + wn + j * 16 + l15) * 32 + quad * 8];
        short8 bN = *(const short8*)&Bs[(384 + wn + j * 16 + l15) * 32 + quad * 8];
#pragma unroll
        for (int i = 0; i < 2; i++) {
          aR[i][j] = __builtin_amdgcn_mfma_f32_16x16x32_bf16(af[i], bR, aR[i][j], 0, 0, 0);
          aZ[i][j] = __builtin_amdgcn_mfma_f32_16x16x32_bf16(af[i], bZ, aZ[i][j], 0, 0, 0);
          aN[i][j] = __builtin_amdgcn_mfma_f32_16x16x32_bf16(af[i], bN, aN[i][j], 0, 0, 0);
        }
      }
      __syncthreads();
    }
  }
  // ---- phase H: R/Z/H accs += Hin @ Whh^T  (K = 192) ----
  if (!t0) {
    const u16* ab = Hin + (size_t)(m0 + wid * 16 + lrow) * 192 + lkc;
    const u16* bb = Whh + (size_t)(wid * 16 + lrow) * 192 + lkc;
#pragma unroll
    for (int kt = 0; kt < 6; ++kt) {
      const int ko = kt * 32;
      gl16(ab + ko, asl);
#pragma unroll
      for (int r = 0; r < 9; r++)
        gl16(bb + (size_t)(r * 64) * 192 + ko, &Bs[(r * 64 + wid * 16) * 32]);
      __syncthreads();
      short8 af[2];
#pragma unroll
      for (int i = 0; i < 2; i++)
        af[i] = *(const short8*)&As[(wm + i * 16 + l15) * 32 + quad * 8];
#pragma unroll
      for (int j = 0; j < 6; j++) {
        short8 bR = *(const short8*)&Bs[(wn + j * 16 + l15) * 32 + quad * 8];
        short8 bZ = *(const short8*)&Bs[(192 + wn + j * 16 + l15) * 32 + quad * 8];
        short8 bN = *(const short8*)&Bs[(384 + wn + j * 16 + l15) * 32 + quad * 8];
#pragma unroll
        for (int i = 0; i < 2; i++) {
          aR[i][j] = __builtin_amdgcn_mfma_f32_16x16x32_bf16(af[i], bR, aR[i][j], 0, 0, 0);
          aZ[i][j] = __builtin_amdgcn_mfma_f32_16x16x32_bf16(af[i], bZ, aZ[i][j], 0, 0, 0);
          aH[i][j] = __builtin_amdgcn_mfma_f32_16x16x32_bf16(af[i], bN, aH[i][j], 0, 0, 0);
        }
      }
      __syncthreads();
    }
  }

  // ---- pass 1: gates, state write, score partials ----
  float ps[2][4];
#pragma unroll
  for (int i = 0; i < 2; i++)
#pragma unroll
    for (int e = 0; e < 4; e++) ps[i][e] = 0.f;

#pragma unroll
  for (int j = 0; j < 6; ++j) {
    const int c = wn + j * 16 + l15;
    const float brz = bih[c] + bhh[c];
    const float bzz = bih[192 + c] + bhh[192 + c];
    const float bxn = bih[384 + c];
    const float bhn = bhh[384 + c];
    const float aw  = POOL ? att_w[c] : 0.f;
#pragma unroll
    for (int i = 0; i < 2; ++i)
#pragma unroll
      for (int e = 0; e < 4; ++e) {
        const int row = m0 + wm + i * 16 + quad * 4 + e;
        float rg  = sigm(aR[i][j][e] + brz);
        float zg  = sigm(aZ[i][j][e] + bzz);
        float hnv = bhn + (t0 ? 0.f : aH[i][j][e]);
        float ng  = tanhf(aN[i][j][e] + bxn + rg * hnv);
        float hold = t0 ? 0.f : bf2f(Hin[(size_t)row * 192 + c]);
        float hnew = (1.f - zg) * ng + zg * hold;
        Hout[(size_t)row * 192 + c] = f2bf(hnew);
        if (POOL) ps[i][e] += hnew * aw;
      }
  }

  if (POOL) {
#pragma unroll
    for (int i = 0; i < 2; ++i)
#pragma unroll
      for (int e = 0; e < 4; ++e) {
        float v = ps[i][e];
        v += __shfl_xor(v, 1); v += __shfl_xor(v, 2);
        v += __shfl_xor(v, 4); v += __shfl_xor(v, 8);
        if (l15 == 0) score_s[wm + i * 16 + quad * 4 + e][wid & 1] = v;
      }
    __syncthreads();
    if (tid < 64) {
      float s = score_s[tid][0] + score_s[tid][1];
      const int q = m0 + tid;
      float so, wnf;
      if (t0) { so = 0.f; wnf = 1.f; Mbuf[q] = s; Lbuf[q] = 1.f; }
      else {
        float Mo = Mbuf[q];
        float Mn = fmaxf(Mo, s);
        so = __expf(Mo - Mn); wnf = __expf(s - Mn);
        Mbuf[q] = Mn; Lbuf[q] = Lbuf[q] * so + wnf;
      }
      bc_s[tid][0] = so; bc_s[tid][1] = wnf;
    }
    __syncthreads();
    // ---- pass 2: recompute hnew, update Nv ----
#pragma unroll
    for (int j = 0; j < 6; ++j) {
      const int c = wn + j * 16 + l15;
      const float brz = bih[c] + bhh[c];
      const float bzz = bih[192 + c] + bhh[192 + c];
      const float bxn = bih[384 + c];
      const float bhn = bhh[384 + c];
#pragma unroll
      for (int i = 0; i < 2; ++i)
#pragma unroll
        for (int e = 0; e < 4; ++e) {
          const int rowl = wm + i * 16 + quad * 4 + e;
          const int row = m0 + rowl;
          float rg  = sigm(aR[i][j][e] + brz);
          float zg  = sigm(aZ[i][j][e] + bzz);
          float hnv = bhn + (t0 ? 0.f : aH[i][j][e]);
          float ng  = tanhf(aN[i][j][e] + bxn + rg * hnv);
          float hold = t0 ? 0.f : bf2f(Hin[(size_t)row * 192 + c]);
          float hnew = (1.f - zg) * ng + zg * hold;
          const float so = bc_s[rowl][0], wnf = bc_s[rowl][1];
          const size_t idx = (size_t)row * 192 + c;
          float prev = t0 ? 0.f : Nv[idx];
          Nv[idx] = prev * so + wnf * hnew;
        }
    }
  }
}

// ============================================================
// H2 GEMM: h2t[(r*96+c2)*1024+n] = Hln @ W2 (analytic LN1 in A-staging)
// Epilogue: LDS-transpose + coalesced dwordx4 stores along n.
// ============================================================
__launch_bounds__(256)
__global__ void k_h2gemm(const float* __restrict__ yt, const float4* __restrict__ cwpk,
                         const u16* __restrict__ W2s, const float* __restrict__ consts,
                         u16* __restrict__ h2t)
{
  constexpr int PK = 40;
  __shared__ u16 As[128 * PK];
  __shared__ u16 Bs[96 * PK];
  __shared__ u16 Ts[96 * 136];   // transpose staging, pitch 136 (16B-aligned rows)

  const int tid  = threadIdx.x;
  const int m0   = blockIdx.x * 128;
  const int wid  = tid >> 6;
  const int lane = tid & 63;
  const int l15  = lane & 15;
  const int quad = lane >> 4;
  const int wm   = (wid >> 1) * 64;
  const int wn   = (wid & 1) * 48;

  const float P = consts[0], Q = consts[1], VW = consts[2], CWB = consts[3], VB = consts[4];

  const int arow = tid >> 2;
  const int akc  = tid & 3;

  float yv[2], mu[2], iv[2];
#pragma unroll
  for (int rr = 0; rr < 2; rr++) {
    int i = m0 + arow + rr * 64;
    int r = i / 1000, n = i - r * 1000;
    float y = yt[n * 384 + r];
    yv[rr] = y;
    mu[rr] = y * P + Q;
    iv[rr] = rsqrtf(y * y * VW + 2.f * y * CWB + VB + 1e-5f);
  }

  float4v acc[4][3];
  const float4v fz = {0.f, 0.f, 0.f, 0.f};
#pragma unroll
  for (int i = 0; i < 4; i++)
#pragma unroll
    for (int j = 0; j < 3; j++) acc[i][j] = fz;

  uint4 asave[2][3];
  const bool has2 = (arow < 32);

  for (int kt = 0; kt < 6; ++kt) {
    const int k0 = kt * 32 + akc * 8;
    uint4 av[2];
    if (kt < 3) {
#pragma unroll
      for (int rr = 0; rr < 2; rr++) {
        u16 hb[8];
#pragma unroll
        for (int e = 0; e < 8; e++) {
          float4 cw = cwpk[k0 + e];
          float t = yv[rr] * cw.x + cw.y - mu[rr];
          float h = fmaxf(t * iv[rr] * cw.z + cw.w, 0.f);
          hb[e] = f2bf(h);
        }
        __builtin_memcpy(&av[rr], hb, 16);
        asave[rr][kt] = av[rr];
      }
    } else {
      av[0] = asave[0][kt - 3];
      av[1] = asave[1][kt - 3];
    }
    uint4 bv0 = *(const uint4*)(W2s + (size_t)arow * 192 + k0);
    uint4 bv1 = make_uint4(0, 0, 0, 0);
    if (has2) bv1 = *(const uint4*)(W2s + (size_t)(arow + 64) * 192 + k0);

    __syncthreads();
    *(uint4*)&As[arow * PK + akc * 8]        = av[0];
    *(uint4*)&As[(arow + 64) * PK + akc * 8] = av[1];
    *(uint4*)&Bs[arow * PK + akc * 8]        = bv0;
    if (has2) *(uint4*)&Bs[(arow + 64) * PK + akc * 8] = bv1;
    __syncthreads();

    short8 af[4], bfr[3];
#pragma unroll
    for (int i = 0; i < 4; i++)
      af[i] = *(const short8*)&As[(wm + i * 16 + l15) * PK + quad * 8];
#pragma unroll
    for (int j = 0; j < 3; j++)
      bfr[j] = *(const short8*)&Bs[(wn + j * 16 + l15) * PK + quad * 8];
#pragma unroll
    for (int i = 0; i < 4; i++)
#pragma unroll
      for (int j = 0; j < 3; j++)
        acc[i][j] = __builtin_amdgcn_mfma_f32_16x16x32_bf16(af[i], bfr[j], acc[i][j], 0, 0, 0);
  }

  // transpose tile into LDS: Ts[c2][row_local]
#pragma unroll
  for (int i = 0; i < 4; i++)
#pragma unroll
    for (int j = 0; j < 3; j++)
#pragma unroll
      for (int e = 0; e < 4; e++) {
        int rowl = wm + i * 16 + quad * 4 + e;
        int c2   = wn + j * 16 + l15;
        Ts[c2 * 136 + rowl] = f2bf(acc[i][j][e]);
      }
  __syncthreads();
  // coalesced stores: 8-wide n-chunks never cross the r-boundary (1000 % 8 == 0)
#pragma unroll
  for (int u = tid; u < 1536; u += 256) {
    int c2 = u >> 4, ch = u & 15;
    int iidx0 = m0 + ch * 8;
    int r = iidx0 / 1000, n0 = iidx0 - r * 1000;
    *(uint4*)(h2t + (size_t)(r * 96 + c2) * 1024 + n0) = *(const uint4*)&Ts[c2 * 136 + ch * 8];
  }
}

// ============================================================
// prep: f32 -> bf16 conversions + W1/b1 moment stats + W2 split + cw pack
// ============================================================
__launch_bounds__(256)
__global__ void k_prep(const float* x, const float* fus_W,
                       const float* Wih0, const float* Whh0,
                       const float* Wih1, const float* Whh1,
                       const float* gcn_W1, const float* gcn_b1,
                       const float* gcn_W2, const float* ln1g, const float* ln1b,
                       u16* xbf, u16* fusWbf, u16* Wih0b, u16* Whh0b, u16* Wih1b, u16* Whh1b,
                       u16* W2s, float4* cwpk, float* consts)
{
  long o = (long)blockIdx.x * 256 + threadIdx.x;
  if (o < 384000) xbf[o] = f2bf(x[o]);
  else if ((o -= 384000) < 32000) fusWbf[o] = f2bf(fus_W[o]);
  else if ((o -= 32000) < 55296)  Wih0b[o] = f2bf(Wih0[o]);
  else if ((o -= 55296) < 110592) Whh0b[o] = f2bf(Whh0[o]);
  else if ((o -= 110592) < 110592) Wih1b[o] = f2bf(Wih1[o]);
  else if ((o -= 110592) < 110592) Whh1b[o] = f2bf(Whh1[o]);
  else if ((o -= 110592) < 9216) {
    int c2 = (int)o / 96, c = (int)o - c2 * 96;
    float wv = gcn_W2[c * 96 + c2];
    u16 hi = f2bf(wv);
    u16 lo = f2bf(wv - bf2f(hi));
    W2s[c2 * 192 + c] = hi;
    W2s[c2 * 192 + 96 + c] = lo;
  }
  else if ((o -= 9216) < 96) {
    int c = (int)o;
    float4 cw;
    cw.x = gcn_W1[c]; cw.y = gcn_b1[c]; cw.z = ln1g[c]; cw.w = ln1b[c];
    cwpk[c] = cw;
  }
  if (blockIdx.x == 0 && threadIdx.x == 0) {
    float sw = 0, sb = 0, sww = 0, swb = 0, sbb = 0;
    for (int c = 0; c < 96; c++) {
      float wv = gcn_W1[c], b = gcn_b1[c];
      sw += wv; sb += b; sww += wv * wv; swb += wv * b; sbb += b * b;
    }
    float P = sw / 96.f, Q = sb / 96.f;
    consts[0] = P; consts[1] = Q;
    consts[2] = sww / 96.f - P * P;
    consts[3] = swb / 96.f - P * Q;
    consts[4] = sbb / 96.f - Q * Q;
  }
}

// zero-fill h2t K-pad columns (1000..1023)
__launch_bounds__(256)
__global__ void k_zero(u16* __restrict__ h2t)
{
  int idx = blockIdx.x * 256 + threadIdx.x;
  if (idx < 110592) {
    int row = idx / 3, p = idx - row * 3;
    *(uint4*)(h2t + (size_t)row * 1024 + 1000 + p * 8) = make_uint4(0, 0, 0, 0);
  }
}

// fc1W (192x192 f32) -> split-bf16 B' (192 x 576): [wh | wl | wh]
__launch_bounds__(256)
__global__ void k_w1split(const float* __restrict__ fc1W, u16* __restrict__ w1s)
{
  int idx = blockIdx.x * 256 + threadIdx.x;
  if (idx >= 192 * 192) return;
  int n = idx / 192, k = idx - n * 192;
  float w = fc1W[idx];
  u16 hi = f2bf(w);
  u16 lo = f2bf(w - bf2f(hi));
  w1s[(size_t)n * 576 + k]       = hi;
  w1s[(size_t)n * 576 + 192 + k] = lo;
  w1s[(size_t)n * 576 + 384 + k] = hi;
}

// ============================================================
// per-row: Aadp softmax row + the 3 candidate graphs (bf16) + row sums
// ============================================================
__launch_bounds__(256)
__global__ void k_adjrow(const float* __restrict__ A, const float* __restrict__ FSP,
                         const float* __restrict__ DSP, const float* __restrict__ E1,
                         const float* __restrict__ E2,
                         const float* beta1, const float* beta2,
                         u16* __restrict__ G, float* __restrict__ rowsums)
{
  __shared__ float z[1000];
  __shared__ float red[256];
  const int n = blockIdx.x, tid = threadIdx.x;

  float e1r[10];
#pragma unroll
  for (int d = 0; d < 10; d++) e1r[d] = E1[n * 10 + d];

  float lmax = -1e30f;
  for (int m = tid; m < 1000; m += 256) {
    float s = 0;
#pragma unroll
    for (int d = 0; d < 10; d++) s += e1r[d] * E2[m * 10 + d];
    s = fmaxf(s, 0.f);
    z[m] = s;
    lmax = fmaxf(lmax, s);
  }
  red[tid] = lmax; __syncthreads();
  for (int st = 128; st > 0; st >>= 1) { if (tid < st) red[tid] = fmaxf(red[tid], red[tid + st]); __syncthreads(); }
  const float mx = red[0]; __syncthreads();

  float lsum = 0;
  for (int m = tid; m < 1000; m += 256) { float e = __expf(z[m] - mx); z[m] = e; lsum += e; }
  red[tid] = lsum; __syncthreads();
  for (int st = 128; st > 0; st >>= 1) { if (tid < st) red[tid] += red[tid + st]; __syncthreads(); }
  const float inv = 1.f / red[0]; __syncthreads();

  const float w1 = sigm(beta1[0]);
  const float w2 = sigm(beta2[0]);
  float s0 = 0, s1 = 0, s2 = 0;
  for (int m = tid; m < 1000; m += 256) {
    float aadp = z[m] * inv;
    float a = A[n * 1000 + m], f = FSP[n * 1000 + m], dd = DSP[n * 1000 + m];
    float g0 = 0.5f * a + 0.5f * aadp;
    float g1 = w1 * a + (1.f - w1) * f;
    float g2 = w2 * a + (1.f - w2) * dd;
    G[0 * 1000000 + n * 1000 + m] = f2bf(g0);
    G[1 * 1000000 + n * 1000 + m] = f2bf(g1);
    G[2 * 1000000 + n * 1000 + m] = f2bf(g2);
    s0 += g0; s1 += g1; s2 += g2;
  }
  red[tid] = s0; __syncthreads();
  for (int st = 128; st > 0; st >>= 1) { if (tid < st) red[tid] += red[tid + st]; __syncthreads(); }
  if (tid == 0) rowsums[n] = red[0];
  __syncthreads();
  red[tid] = s1; __syncthreads();
  for (int st = 128; st > 0; st >>= 1) { if (tid < st) red[tid] += red[tid + st]; __syncthreads(); }
  if (tid == 0) rowsums[1000 + n] = red[0];
  __syncthreads();
  red[tid] = s2; __syncthreads();
  for (int st = 128; st > 0; st >>= 1) { if (tid < st) red[tid] += red[tid + st]; __syncthreads(); }
  if (tid == 0) rowsums[2000 + n] = red[0];
}

// sc[k] = mean_n( sum_a tanh(P[k,n,a]+fus_b[a]) * fus_v[a] )
__launch_bounds__(256)
__global__ void k_sc(const float* __restrict__ P, const float* fus_b, const float* fus_v, float* sc)
{
  __shared__ float red[256];
  const int k = blockIdx.x, tid = threadIdx.x;
  float local = 0;
  for (int n = tid; n < 1000; n += 256) {
    const float* p = P + (size_t)(k * 1000 + n) * 32;
    float s = 0;
#pragma unroll
    for (int a = 0; a < 32; a++) s += tanhf(p[a] + fus_b[a]) * fus_v[a];
    local += s;
  }
  red[tid] = local; __syncthreads();
  for (int st = 128; st > 0; st >>= 1) { if (tid < st) red[tid] += red[tid + st]; __syncthreads(); }
  if (tid == 0) sc[k] = red[0] * (1.f / 1000.f);
}

__launch_bounds__(256)
__global__ void k_alpha(const float* sc, const float* rowsums, float* alpha_out, float* dinv)
{
  __shared__ float al[3];
  const int tid = threadIdx.x;
  if (tid == 0) {
    float m = fmaxf(sc[0], fmaxf(sc[1], sc[2]));
    float e0 = __expf(sc[0] - m), e1 = __expf(sc[1] - m), e2 = __expf(sc[2] - m);
    float inv = 1.f / (e0 + e1 + e2);
    al[0] = e0 * inv; al[1] = e1 * inv; al[2] = e2 * inv;
    alpha_out[0] = al[0]; alpha_out[1] = al[1]; alpha_out[2] = al[2];
  }
  __syncthreads();
  const float a0 = al[0], a1 = al[1], a2 = al[2];
  for (int n = tid; n < 1000; n += 256) {
    float d = a0 * rowsums[n] + a1 * rowsums[1000 + n] + a2 * rowsums[2000 + n] + 1.0f;
    dinv[n] = rsqrtf(fmaxf(d, 1e-12f));
  }
}

// S_hat -> Sbf with 1024 K-pad stride (pad cols zeroed)
__launch_bounds__(256)
__global__ void k_shat(const u16* __restrict__ G, const float* alpha, const float* dinv,
                       u16* __restrict__ S)
{
  int idx = blockIdx.x * 256 + threadIdx.x;
  if (idx >= 1024000) return;
  int i = idx >> 10, j = idx & 1023;
  u16 val = 0;
  if (j < 1000) {
    const float a0 = alpha[0], a1 = alpha[1], a2 = alpha[2];
    int g = i * 1000 + j;
    float mg = a0 * bf2f(G[g]) + a1 * bf2f(G[1000000 + g]) + a2 * bf2f(G[2000000 + g]);
    if (i == j) mg += 1.0f;
    val = f2bf(mg * dinv[i] * dinv[j]);
  }
  S[(size_t)i * 1024 + j] = val;
}

// In-place LN2 over 96 ch on g-layout buffer
__launch_bounds__(256)
__global__ void k_ln2g(u16* __restrict__ g, const float* __restrict__ b2,
                       const float* __restrict__ g2, const float* __restrict__ be2)
{
  const int i = blockIdx.x * 256 + threadIdx.x;
  if (i >= 384000) return;
  u16* row = g + (size_t)i * 96;

  uint4 raw[12];
#pragma unroll
  for (int t = 0; t < 12; t++) raw[t] = *(const uint4*)((const u16*)row + t * 8);

  float s = 0, ss = 0;
#pragma unroll
  for (int t = 0; t < 12; t++) {
    const u16* ch = (const u16*)&raw[t];
#pragma unroll
    for (int e = 0; e < 8; e++) {
      float v = bf2f(ch[e]) + b2[t * 8 + e];
      s += v; ss += v * v;
    }
  }
  const float mean = s * (1.f / 96.f);
  const float var  = ss * (1.f / 96.f) - mean * mean;
  const float isd  = rsqrtf(var + 1e-5f);

#pragma unroll
  for (int t = 0; t < 12; t++) {
    const u16* ch = (const u16*)&raw[t];
#pragma unroll
    for (int p = 0; p < 2; p++) {
      int c0 = t * 8 + p * 4;
      u32 w0 = f2bf((bf2f(ch[p * 4 + 0]) + b2[c0 + 0] - mean) * isd * g2[c0 + 0] + be2[c0 + 0]);
      u32 w1 = f2bf((bf2f(ch[p * 4 + 1]) + b2[c0 + 1] - mean) * isd * g2[c0 + 1] + be2[c0 + 1]);
      u32 w2 = f2bf((bf2f(ch[p * 4 + 2]) + b2[c0 + 2] - mean) * isd * g2[c0 + 2] + be2[c0 + 2]);
      u32 w3 = f2bf((bf2f(ch[p * 4 + 3]) + b2[c0 + 3] - mean) * isd * g2[c0 + 3] + be2[c0 + 3]);
      ((u32*)row)[t * 4 + p * 2 + 0] = (w0 | (w1 << 16));
      ((u32*)row)[t * 4 + p * 2 + 1] = (w2 | (w3 << 16));
    }
  }
}

// ctx = Nv/L, split to hi/lo bf16, pack A' rows [ch | ch | cl] (K=576)
__launch_bounds__(256)
__global__ void k_ctxsplit(const float* __restrict__ Nv, const float* __restrict__ Lbuf,
                           u16* __restrict__ ctxs)
{
  const int i = blockIdx.x * 256 + threadIdx.x;
  if (i >= 32000 * 192) return;
  const int q = i / 192, c = i - q * 192;
  float v = Nv[i] / Lbuf[q];
  u16 hi = f2bf(v);
  u16 lo = f2bf(v - bf2f(hi));
  u16* row = ctxs + (size_t)q * 576;
  row[c] = hi; row[192 + c] = hi; row[384 + c] = lo;
}

// fc2: LDS-staged tiny GEMM + transposed store
__launch_bounds__(192)
__global__ void k_fc2(const float* __restrict__ hfc, const float* __restrict__ fc2W,
                      const float* __restrict__ fc2b, float* __restrict__ out)
{
  __shared__ float w2S[12][193];
  __shared__ float hS[16][193];
  const int tid = threadIdx.x;
  const int q0 = blockIdx.x * 16;
  for (int idx = tid; idx < 12 * 192; idx += 192) {
    int o = idx / 192, k = idx - o * 192;
    w2S[o][k] = fc2W[idx];
  }
  for (int idx = tid; idx < 16 * 192; idx += 192) {
    int qq = idx / 192, k = idx - qq * 192;
    hS[qq][k] = hfc[(size_t)(q0 + qq) * 192 + k];
  }
  __syncthreads();
  const int qq = tid / 12, o = tid - qq * 12;
  float acc = fc2b[o];
#pragma unroll 8
  for (int k = 0; k < 192; k++) acc += hS[qq][k] * w2S[o][k];
  const int q = q0 + qq;
  const int b = q / 1000, node = q - b * 1000;
  out[(size_t)b * 12000 + o * 1000 + node] = acc;
}

// ============================================================
extern "C" void kernel_launch(void* const* d_in, const int* in_sizes, int n_in,
                              void* d_out, int out_size, void* d_ws, size_t ws_size,
                              hipStream_t stream)
{
  const float* x     = (const float*)d_in[0];
  const float* A     = (const float*)d_in[1];
  const float* FSP   = (const float*)d_in[2];
  const float* DSP   = (const float*)d_in[3];
  const float* E1    = (const float*)d_in[4];
  const float* E2    = (const float*)d_in[5];
  const float* fus_W = (const float*)d_in[6];
  const float* fus_b = (const float*)d_in[7];
  const float* fus_v = (const float*)d_in[8];
  const float* beta1 = (const float*)d_in[9];
  const float* beta2 = (const float*)d_in[10];
  const float* gcn_W1= (const float*)d_in[11];
  const float* gcn_b1= (const float*)d_in[12];
  const float* ln1g  = (const float*)d_in[13];
  const float* ln1b  = (const float*)d_in[14];
  const float* gcn_W2= (const float*)d_in[15];
  const float* gcn_b2= (const float*)d_in[16];
  const float* ln2g  = (const float*)d_in[17];
  const float* ln2b  = (const float*)d_in[18];
  const float* Wih0  = (const float*)d_in[19];
  const float* Whh0  = (const float*)d_in[20];
  const float* bih0  = (const float*)d_in[21];
  const float* bhh0  = (const float*)d_in[22];
  const float* Wih1  = (const float*)d_in[23];
  const float* Whh1  = (const float*)d_in[24];
  const float* bih1  = (const float*)d_in[25];
  const float* bhh1  = (const float*)d_in[26];
  const float* att_w = (const float*)d_in[27];
  const float* fc1W  = (const float*)d_in[28];
  const float* fc1b  = (const float*)d_in[29];
  const float* fc2W  = (const float*)d_in[30];
  const float* fc2b  = (const float*)d_in[31];
  float* out = (float*)d_out;

  char* w = (char*)d_ws;
  auto alloc = [&](size_t bytes) -> char* {
    char* p = w;
    w += (bytes + 255) & ~(size_t)255;
    return p;
  };

  float* consts  = (float*)alloc(8 * 4);
  float* scp     = (float*)alloc(3 * 4);
  float* alphap  = (float*)alloc(3 * 4);
  float* rowsums = (float*)alloc(3000 * 4);
  float* dinvp   = (float*)alloc(1000 * 4);
  u16*   Gbuf    = (u16*)alloc((size_t)3000000 * 2);
  u16*   Sbf     = (u16*)alloc((size_t)1024 * 1024 * 2);
  u16*   xbf     = (u16*)alloc((size_t)384000 * 2);
  u16*   fusWbf  = (u16*)alloc((size_t)32000 * 2);
  u16*   Wih0b   = (u16*)alloc((size_t)55296 * 2);
  u16*   Whh0b   = (u16*)alloc((size_t)110592 * 2);
  u16*   Wih1b   = (u16*)alloc((size_t)110592 * 2);
  u16*   Whh1b   = (u16*)alloc((size_t)110592 * 2);
  u16*   w1s     = (u16*)alloc((size_t)192 * 576 * 2);
  u16*   W2s     = (u16*)alloc((size_t)96 * 192 * 2);
  float4* cwpk   = (float4*)alloc((size_t)96 * 16);
  float* Pbuf    = (float*)alloc((size_t)96000 * 4);
  float* yt      = (float*)alloc((size_t)384000 * 4);
  u16*   h2t     = (u16*)alloc((size_t)36864 * 1024 * 2);  // 75.5 MB; states/FC alias later
  u16*   Gg      = (u16*)alloc((size_t)36864000 * 2);      // 73.7 MB
  float* Nv      = (float*)alloc((size_t)6144000 * 4);
  float* Mbuf    = (float*)alloc((size_t)32000 * 4);
  float* Lbuf    = (float*)alloc((size_t)32000 * 4);

  // GRU state double-buffers alias the h2t region (dead after k_bigemm)
  u16* h0buf[2] = { h2t,                    h2t + (size_t)6144000 };
  u16* h1buf[2] = { h2t + (size_t)12288000, h2t + (size_t)18432000 };
  // FC-head aliases (states dead after GRU loop)
  u16*   ctxs = h2t;
  float* hfc  = (float*)(h2t + (size_t)18432000);

  k_prep<<<3174, 256, 0, stream>>>(x, fus_W, Wih0, Whh0, Wih1, Whh1, gcn_W1, gcn_b1,
                                   gcn_W2, ln1g, ln1b,
                                   xbf, fusWbf, Wih0b, Whh0b, Wih1b, Whh1b, W2s, cwpk, consts);
  k_w1split<<<144, 256, 0, stream>>>(fc1W, w1s);
  k_zero<<<432, 256, 0, stream>>>(h2t);
  k_adjrow<<<1000, 256, 0, stream>>>(A, FSP, DSP, E1, E2, beta1, beta2, Gbuf, rowsums);
  gemm_nt<0><<<dim3(1, 24), 256, 0, stream>>>(Gbuf, 1000, fusWbf, 1000, Pbuf, 32, 3000, 32, 1000, nullptr);
  k_sc<<<3, 256, 0, stream>>>(Pbuf, fus_b, fus_v, scp);
  k_alpha<<<1, 256, 0, stream>>>(scp, rowsums, alphap, dinvp);
  k_shat<<<4000, 256, 0, stream>>>(Gbuf, alphap, dinvp, Sbf);
  // yt[m, r] = sum_n S[m,n] * x[r,n]
  gemm_nt<0><<<dim3(6, 8), 256, 0, stream>>>(Sbf, 1024, xbf, 1000, yt, 384, 1000, 384, 1000, nullptr);
  // h2t = Hln @ W2 (LN1 fused, LDS-transposed coalesced stores)
  k_h2gemm<<<3000, 256, 0, stream>>>(yt, cwpk, W2s, consts, h2t);
  // Gg = S @ h2t^T  (73.7 GFLOP)
  k_bigemm<<<2304, 256, 0, stream>>>(Sbf, h2t, Gg);
  k_ln2g<<<1500, 256, 0, stream>>>(Gg, gcn_b2, ln2g, ln2b);

  for (int t = 0; t < 12; ++t) {
    u16* h0in  = h0buf[t & 1];
    u16* h0out = h0buf[(t & 1) ^ 1];
    u16* h1in  = h1buf[t & 1];
    u16* h1out = h1buf[(t & 1) ^ 1];
    k_gru<96, false><<<500, 256, 0, stream>>>(
        Gg + t * 96, 1152, Wih0b, h0in, Whh0b, bih0, bhh0, h0out,
        nullptr, nullptr, nullptr, nullptr, t == 0);
    k_gru<192, true><<<500, 256, 0, stream>>>(
        h0out, 192, Wih1b, h1in, Whh1b, bih1, bhh1, h1out,
        att_w, Mbuf, Lbuf, Nv, t == 0);
  }

  // FC head
  k_ctxsplit<<<24000, 256, 0, stream>>>(Nv, Lbuf, ctxs);
  gemm_nt<3><<<dim3(3, 250), 256, 0, stream>>>(ctxs, 576, w1s, 576, hfc, 192, 32000, 192, 576, fc1b);
  k_fc2<<<2000, 192, 0, stream>>>(hfc, fc2W, fc2b, out);
}

// Round 7
// 2125.800 us; speedup vs baseline: 1.8578x; 1.8578x over previous
//
#include <hip/hip_runtime.h>

typedef unsigned short u16;
typedef unsigned int u32;
typedef __attribute__((ext_vector_type(8))) short short8;   // 8 x bf16 (4 VGPRs)
typedef __attribute__((ext_vector_type(4))) float float4v;  // 4 x f32

#define DEV static __device__ __forceinline__

DEV float bf2f(u16 u) { u32 x = ((u32)u) << 16; float f; __builtin_memcpy(&f, &x, 4); return f; }
DEV u16 f2bf(float f) {
  u32 u; __builtin_memcpy(&u, &f, 4);
  u = (u + 0x7fffu + ((u >> 16) & 1u)) >> 16;
  return (u16)u;
}
DEV float sigm(float x) { return 1.f / (1.f + __expf(-x)); }

// async global->LDS, 16B per lane; LDS dest = wave-uniform base + lane*16
DEV void gl16(const u16* g, u16* l) {
  __builtin_amdgcn_global_load_lds(
      (const __attribute__((address_space(1))) void*)g,
      (__attribute__((address_space(3))) void*)l, 16, 0, 0);
}

// ============================================================
// Generic GEMM (small cases): C[M,N] = A[M,K](bf16) * B[N,K](bf16 "NK")
// OMODE: 0 = f32 row-major, 3 = f32 + bias + tanh-GELU epilogue (fc1)
// ============================================================
template <int OMODE>
__launch_bounds__(256)
__global__ void gemm_nt(const u16* __restrict__ A, int lda,
                        const u16* __restrict__ B, int ldb,
                        void* __restrict__ Cp, int ldc,
                        int M, int N, int K,
                        const float* __restrict__ bias)
{
  constexpr int PK = 40;
  __shared__ u16 As[128 * PK];
  __shared__ u16 Bs[64 * PK];

  const int tid  = threadIdx.x;
  const int m0   = blockIdx.y * 128;
  const int n0   = blockIdx.x * 64;
  const int wid  = tid >> 6;
  const int lane = tid & 63;
  const int l15  = lane & 15;
  const int quad = lane >> 4;
  const int wm   = (wid >> 1) * 64;
  const int wn   = (wid & 1) * 32;

  float4v acc[4][2];
  const float4v fz = {0.f, 0.f, 0.f, 0.f};
#pragma unroll
  for (int i = 0; i < 4; i++)
#pragma unroll
    for (int j = 0; j < 2; j++) acc[i][j] = fz;

  const int arow = tid >> 2;
  const int akc  = tid & 3;

  const int kt_count = (K + 31) / 32;
  for (int kt = 0; kt < kt_count; ++kt) {
    const int k0 = kt * 32 + akc * 8;
    const bool kok = (k0 < K);
    uint4 av0 = make_uint4(0, 0, 0, 0), av1 = av0, bv = av0;
    int ra = m0 + arow;
    if (kok && ra < M)        av0 = *(const uint4*)(A + (size_t)ra * lda + k0);
    if (kok && ra + 64 < M)   av1 = *(const uint4*)(A + (size_t)(ra + 64) * lda + k0);
    int rb = n0 + arow;
    if (kok && rb < N)        bv  = *(const uint4*)(B + (size_t)rb * ldb + k0);

    __syncthreads();
    *(uint4*)&As[arow * PK + akc * 8]        = av0;
    *(uint4*)&As[(arow + 64) * PK + akc * 8] = av1;
    *(uint4*)&Bs[arow * PK + akc * 8]        = bv;
    __syncthreads();

    short8 af[4], bfr[2];
#pragma unroll
    for (int i = 0; i < 4; i++)
      af[i] = *(const short8*)&As[(wm + i * 16 + l15) * PK + quad * 8];
#pragma unroll
    for (int j = 0; j < 2; j++)
      bfr[j] = *(const short8*)&Bs[(wn + j * 16 + l15) * PK + quad * 8];
#pragma unroll
    for (int i = 0; i < 4; i++)
#pragma unroll
      for (int j = 0; j < 2; j++)
        acc[i][j] = __builtin_amdgcn_mfma_f32_16x16x32_bf16(af[i], bfr[j], acc[i][j], 0, 0, 0);
  }

#pragma unroll
  for (int i = 0; i < 4; i++)
#pragma unroll
    for (int j = 0; j < 2; j++)
#pragma unroll
      for (int e = 0; e < 4; e++) {
        int r = m0 + wm + i * 16 + quad * 4 + e;
        int c = n0 + wn + j * 16 + l15;
        if (r < M && c < N) {
          float v = acc[i][j][e];
          if (OMODE == 0) ((float*)Cp)[(size_t)r * ldc + c] = v;
          else {
            float a = v + bias[c];
            float t = tanhf(0.7978845608028654f * (a + 0.044715f * a * a * a));
            ((float*)Cp)[(size_t)r * ldc + c] = 0.5f * a * (1.f + t);
          }
        }
      }
}

// ============================================================
// Big graph-conv GEMM: Gg = S(1000x1024) @ h2t(36864x1024)^T
// 128x128x32, global_load_lds(16B), XCD swizzle, g-layout scatter.
// ============================================================
__launch_bounds__(256)
__global__ void k_bigemm(const u16* __restrict__ A,
                         const u16* __restrict__ B,
                         u16* __restrict__ Gg)
{
  __shared__ u16 As[128 * 32];
  __shared__ u16 Bs[128 * 32];
  const int tid  = threadIdx.x;
  const int bid  = blockIdx.x;
  const int xcd  = bid & 7;
  const int jj   = bid >> 3;
  const int m0   = (jj & 7) * 128;
  const int n0   = (xcd + 8 * (jj >> 3)) * 128;

  const int wid  = tid >> 6;
  const int lane = tid & 63;
  const int l15  = lane & 15;
  const int quad = lane >> 4;
  const int wm   = (wid >> 1) * 64;
  const int wn   = (wid & 1) * 64;

  const int srow = wid * 16 + (lane >> 2);
  const int skc  = (lane & 3) * 8;

  const u16* agp0 = A + (size_t)(m0 + srow) * 1024 + skc;
  const u16* agp1 = agp0 + (size_t)64 * 1024;
  const u16* bgp0 = B + (size_t)(n0 + srow) * 1024 + skc;
  const u16* bgp1 = bgp0 + (size_t)64 * 1024;
  u16* asl0 = &As[(wid * 16) * 32];
  u16* asl1 = &As[(64 + wid * 16) * 32];
  u16* bsl0 = &Bs[(wid * 16) * 32];
  u16* bsl1 = &Bs[(64 + wid * 16) * 32];

  float4v acc[4][4];
  const float4v fz = {0.f, 0.f, 0.f, 0.f};
#pragma unroll
  for (int i = 0; i < 4; i++)
#pragma unroll
    for (int j = 0; j < 4; j++) acc[i][j] = fz;

  for (int kt = 0; kt < 32; ++kt) {
    const int ko = kt * 32;
    gl16(agp0 + ko, asl0);
    gl16(agp1 + ko, asl1);
    gl16(bgp0 + ko, bsl0);
    gl16(bgp1 + ko, bsl1);
    __syncthreads();
    short8 af[4], bf[4];
#pragma unroll
    for (int i = 0; i < 4; i++)
      af[i] = *(const short8*)&As[(wm + i * 16 + l15) * 32 + quad * 8];
#pragma unroll
    for (int j = 0; j < 4; j++)
      bf[j] = *(const short8*)&Bs[(wn + j * 16 + l15) * 32 + quad * 8];
#pragma unroll
    for (int i = 0; i < 4; i++)
#pragma unroll
      for (int j = 0; j < 4; j++)
        acc[i][j] = __builtin_amdgcn_mfma_f32_16x16x32_bf16(af[i], bf[j], acc[i][j], 0, 0, 0);
    __syncthreads();
  }

#pragma unroll
  for (int i = 0; i < 4; i++)
#pragma unroll
    for (int j = 0; j < 4; j++)
#pragma unroll
      for (int e = 0; e < 4; e++) {
        int r = m0 + wm + i * 16 + quad * 4 + e;
        if (r < 1000) {
          int c = n0 + wn + j * 16 + l15;
          int rs = c / 96, cc = c - rs * 96;
          Gg[(size_t)rs * 96000 + (size_t)r * 96 + cc] = f2bf(acc[i][j][e]);
        }
      }
}

// ============================================================
// Fused GRU step (R4 shape: BM=128, 64 cols per gate, grid (3,250)).
// 4 acc tile-sets [4][2] = 128 acc VGPRs — keeps occupancy healthy.
// POOL: partial attention scores via butterfly + atomicAdd.
// ============================================================
template <int KX, bool POOL>
__launch_bounds__(256)
__global__ void k_gru(const u16* __restrict__ Xin, int ldx,
                      const u16* __restrict__ Win,
                      const u16* __restrict__ Hin,
                      const u16* __restrict__ Whh,
                      const float* __restrict__ bih, const float* __restrict__ bhh,
                      u16* __restrict__ Hout,
                      const float* __restrict__ att_w, float* __restrict__ score,
                      int t0)
{
  __shared__ u16 As[128 * 32];
  __shared__ u16 Bs[192 * 32];
  const int tid  = threadIdx.x;
  const int m0   = blockIdx.y * 128;
  const int c0   = blockIdx.x * 64;
  const int wid  = tid >> 6;
  const int lane = tid & 63;
  const int l15  = lane & 15;
  const int quad = lane >> 4;
  const int wm   = (wid >> 1) * 64;
  const int wn   = (wid & 1) * 32;
  const int srow = wid * 16 + (lane >> 2);
  const int skc  = (lane & 3) * 8;

  float4v aR[4][2], aZ[4][2], aXN[4][2], aHN[4][2];
  const float4v fz = {0.f, 0.f, 0.f, 0.f};
#pragma unroll
  for (int i = 0; i < 4; i++)
#pragma unroll
    for (int j = 0; j < 2; j++) { aR[i][j] = fz; aZ[i][j] = fz; aXN[i][j] = fz; aHN[i][j] = fz; }

  u16* asl0 = &As[(wid * 16) * 32];
  u16* asl1 = &As[(64 + wid * 16) * 32];
  u16* bsl0 = &Bs[(wid * 16) * 32];
  u16* bsl1 = &Bs[(64 + wid * 16) * 32];
  u16* bsl2 = &Bs[(128 + wid * 16) * 32];

  // ---- phase X: acc += X @ Win^T ----
  {
    const u16* ax0 = Xin + (size_t)(m0 + srow) * ldx + skc;
    const u16* ax1 = Xin + (size_t)(m0 + 64 + srow) * ldx + skc;
    const u16* bx0 = Win + (size_t)(c0 + srow) * KX + skc;
    const u16* bx1 = Win + (size_t)(192 + c0 + srow) * KX + skc;
    const u16* bx2 = Win + (size_t)(384 + c0 + srow) * KX + skc;
#pragma unroll
    for (int kt = 0; kt < KX / 32; ++kt) {
      const int ko = kt * 32;
      gl16(ax0 + ko, asl0); gl16(ax1 + ko, asl1);
      gl16(bx0 + ko, bsl0); gl16(bx1 + ko, bsl1); gl16(bx2 + ko, bsl2);
      __syncthreads();
      short8 af[4], bR[2], bZ[2], bN[2];
#pragma unroll
      for (int i = 0; i < 4; i++)
        af[i] = *(const short8*)&As[(wm + i * 16 + l15) * 32 + quad * 8];
#pragma unroll
      for (int j = 0; j < 2; j++) {
        bR[j] = *(const short8*)&Bs[(wn + j * 16 + l15) * 32 + quad * 8];
        bZ[j] = *(const short8*)&Bs[(64 + wn + j * 16 + l15) * 32 + quad * 8];
        bN[j] = *(const short8*)&Bs[(128 + wn + j * 16 + l15) * 32 + quad * 8];
      }
#pragma unroll
      for (int i = 0; i < 4; i++)
#pragma unroll
        for (int j = 0; j < 2; j++) {
          aR[i][j]  = __builtin_amdgcn_mfma_f32_16x16x32_bf16(af[i], bR[j], aR[i][j], 0, 0, 0);
          aZ[i][j]  = __builtin_amdgcn_mfma_f32_16x16x32_bf16(af[i], bZ[j], aZ[i][j], 0, 0, 0);
          aXN[i][j] = __builtin_amdgcn_mfma_f32_16x16x32_bf16(af[i], bN[j], aXN[i][j], 0, 0, 0);
        }
      __syncthreads();
    }
  }
  // ---- phase H: acc += Hin @ Whh^T ----
  if (!t0) {
    const u16* ah0 = Hin + (size_t)(m0 + srow) * 192 + skc;
    const u16* ah1 = Hin + (size_t)(m0 + 64 + srow) * 192 + skc;
    const u16* bh0 = Whh + (size_t)(c0 + srow) * 192 + skc;
    const u16* bh1 = Whh + (size_t)(192 + c0 + srow) * 192 + skc;
    const u16* bh2 = Whh + (size_t)(384 + c0 + srow) * 192 + skc;
#pragma unroll
    for (int kt = 0; kt < 6; ++kt) {
      const int ko = kt * 32;
      gl16(ah0 + ko, asl0); gl16(ah1 + ko, asl1);
      gl16(bh0 + ko, bsl0); gl16(bh1 + ko, bsl1); gl16(bh2 + ko, bsl2);
      __syncthreads();
      short8 af[4], bR[2], bZ[2], bN[2];
#pragma unroll
      for (int i = 0; i < 4; i++)
        af[i] = *(const short8*)&As[(wm + i * 16 + l15) * 32 + quad * 8];
#pragma unroll
      for (int j = 0; j < 2; j++) {
        bR[j] = *(const short8*)&Bs[(wn + j * 16 + l15) * 32 + quad * 8];
        bZ[j] = *(const short8*)&Bs[(64 + wn + j * 16 + l15) * 32 + quad * 8];
        bN[j] = *(const short8*)&Bs[(128 + wn + j * 16 + l15) * 32 + quad * 8];
      }
#pragma unroll
      for (int i = 0; i < 4; i++)
#pragma unroll
        for (int j = 0; j < 2; j++) {
          aR[i][j]  = __builtin_amdgcn_mfma_f32_16x16x32_bf16(af[i], bR[j], aR[i][j], 0, 0, 0);
          aZ[i][j]  = __builtin_amdgcn_mfma_f32_16x16x32_bf16(af[i], bZ[j], aZ[i][j], 0, 0, 0);
          aHN[i][j] = __builtin_amdgcn_mfma_f32_16x16x32_bf16(af[i], bN[j], aHN[i][j], 0, 0, 0);
        }
      __syncthreads();
    }
  }

  // ---- epilogue: gates + state write (+ pooling partials) ----
  float ps[4][4];
  if (POOL) {
#pragma unroll
    for (int i = 0; i < 4; i++)
#pragma unroll
      for (int e = 0; e < 4; e++) ps[i][e] = 0.f;
  }
#pragma unroll
  for (int j = 0; j < 2; ++j) {
    const int c = c0 + wn + j * 16 + l15;
    const float brz = bih[c] + bhh[c];
    const float bzz = bih[192 + c] + bhh[192 + c];
    const float bxn = bih[384 + c];
    const float bhn = bhh[384 + c];
    const float aw  = POOL ? att_w[c] : 0.f;
#pragma unroll
    for (int i = 0; i < 4; ++i)
#pragma unroll
      for (int e = 0; e < 4; ++e) {
        const int row = m0 + wm + i * 16 + quad * 4 + e;
        float rg  = sigm(aR[i][j][e] + brz);
        float zg  = sigm(aZ[i][j][e] + bzz);
        float hnv = bhn + (t0 ? 0.f : aHN[i][j][e]);
        float ng  = tanhf(aXN[i][j][e] + bxn + rg * hnv);
        float hold = t0 ? 0.f : bf2f(Hin[(size_t)row * 192 + c]);
        float hnew = (1.f - zg) * ng + zg * hold;
        Hout[(size_t)row * 192 + c] = f2bf(hnew);
        if (POOL) ps[i][e] += hnew * aw;
      }
  }
  if (POOL) {
#pragma unroll
    for (int i = 0; i < 4; ++i)
#pragma unroll
      for (int e = 0; e < 4; ++e) {
        float v = ps[i][e];
        v += __shfl_xor(v, 1); v += __shfl_xor(v, 2);
        v += __shfl_xor(v, 4); v += __shfl_xor(v, 8);
        if (l15 == 0) atomicAdd(&score[m0 + wm + i * 16 + quad * 4 + e], v);
      }
  }
}

// online-softmax pooling update per sequence row q
__launch_bounds__(192)
__global__ void k_pool(const u16* __restrict__ H, float* __restrict__ score,
                       float* __restrict__ Mbuf, float* __restrict__ Lbuf,
                       float* __restrict__ Nv, int t0)
{
  const int q = blockIdx.x, c = threadIdx.x;
  const int i = q * 192 + c;
  const float s = score[q];
  const float hnew = bf2f(H[i]);
  float Mo = 0.f, Lo = 0.f, prev = 0.f;
  if (!t0) { Mo = Mbuf[q]; Lo = Lbuf[q]; prev = Nv[i]; }
  __syncthreads();
  float so, wn;
  if (t0) {
    so = 0.f; wn = 1.f;
    if (c == 0) { Mbuf[q] = s; Lbuf[q] = 1.f; }
  } else {
    float Mn = fmaxf(Mo, s);
    so = __expf(Mo - Mn); wn = __expf(s - Mn);
    if (c == 0) { Mbuf[q] = Mn; Lbuf[q] = Lo * so + wn; }
  }
  if (c == 0) score[q] = 0.f;
  Nv[i] = prev * so + wn * hnew;
}

// ============================================================
// H2 GEMM: h2t[(r*96+c2)*1024+n] = Hln @ W2 (analytic LN1 in A-staging)
// Epilogue: LDS-transpose + coalesced dwordx4 stores along n.
// ============================================================
__launch_bounds__(256)
__global__ void k_h2gemm(const float* __restrict__ yt, const float4* __restrict__ cwpk,
                         const u16* __restrict__ W2s, const float* __restrict__ consts,
                         u16* __restrict__ h2t)
{
  constexpr int PK = 40;
  __shared__ u16 As[128 * PK];
  __shared__ u16 Bs[96 * PK];
  __shared__ u16 Ts[96 * 136];   // transpose staging, pitch 136 (16B-aligned rows)

  const int tid  = threadIdx.x;
  const int m0   = blockIdx.x * 128;
  const int wid  = tid >> 6;
  const int lane = tid & 63;
  const int l15  = lane & 15;
  const int quad = lane >> 4;
  const int wm   = (wid >> 1) * 64;
  const int wn   = (wid & 1) * 48;

  const float P = consts[0], Q = consts[1], VW = consts[2], CWB = consts[3], VB = consts[4];

  const int arow = tid >> 2;
  const int akc  = tid & 3;

  float yv[2], mu[2], iv[2];
#pragma unroll
  for (int rr = 0; rr < 2; rr++) {
    int i = m0 + arow + rr * 64;
    int r = i / 1000, n = i - r * 1000;
    float y = yt[n * 384 + r];
    yv[rr] = y;
    mu[rr] = y * P + Q;
    iv[rr] = rsqrtf(y * y * VW + 2.f * y * CWB + VB + 1e-5f);
  }

  float4v acc[4][3];
  const float4v fz = {0.f, 0.f, 0.f, 0.f};
#pragma unroll
  for (int i = 0; i < 4; i++)
#pragma unroll
    for (int j = 0; j < 3; j++) acc[i][j] = fz;

  uint4 asave[2][3];
  const bool has2 = (arow < 32);

  for (int kt = 0; kt < 6; ++kt) {
    const int k0 = kt * 32 + akc * 8;
    uint4 av[2];
    if (kt < 3) {
#pragma unroll
      for (int rr = 0; rr < 2; rr++) {
        u16 hb[8];
#pragma unroll
        for (int e = 0; e < 8; e++) {
          float4 cw = cwpk[k0 + e];
          float t = yv[rr] * cw.x + cw.y - mu[rr];
          float h = fmaxf(t * iv[rr] * cw.z + cw.w, 0.f);
          hb[e] = f2bf(h);
        }
        __builtin_memcpy(&av[rr], hb, 16);
        asave[rr][kt] = av[rr];
      }
    } else {
      av[0] = asave[0][kt - 3];
      av[1] = asave[1][kt - 3];
    }
    uint4 bv0 = *(const uint4*)(W2s + (size_t)arow * 192 + k0);
    uint4 bv1 = make_uint4(0, 0, 0, 0);
    if (has2) bv1 = *(const uint4*)(W2s + (size_t)(arow + 64) * 192 + k0);

    __syncthreads();
    *(uint4*)&As[arow * PK + akc * 8]        = av[0];
    *(uint4*)&As[(arow + 64) * PK + akc * 8] = av[1];
    *(uint4*)&Bs[arow * PK + akc * 8]        = bv0;
    if (has2) *(uint4*)&Bs[(arow + 64) * PK + akc * 8] = bv1;
    __syncthreads();

    short8 af[4], bfr[3];
#pragma unroll
    for (int i = 0; i < 4; i++)
      af[i] = *(const short8*)&As[(wm + i * 16 + l15) * PK + quad * 8];
#pragma unroll
    for (int j = 0; j < 3; j++)
      bfr[j] = *(const short8*)&Bs[(wn + j * 16 + l15) * PK + quad * 8];
#pragma unroll
    for (int i = 0; i < 4; i++)
#pragma unroll
      for (int j = 0; j < 3; j++)
        acc[i][j] = __builtin_amdgcn_mfma_f32_16x16x32_bf16(af[i], bfr[j], acc[i][j], 0, 0, 0);
  }

  // transpose tile into LDS: Ts[c2][row_local]
#pragma unroll
  for (int i = 0; i < 4; i++)
#pragma unroll
    for (int j = 0; j < 3; j++)
#pragma unroll
      for (int e = 0; e < 4; e++) {
        int rowl = wm + i * 16 + quad * 4 + e;
        int c2   = wn + j * 16 + l15;
        Ts[c2 * 136 + rowl] = f2bf(acc[i][j][e]);
      }
  __syncthreads();
  // coalesced stores: 8-wide n-chunks never cross the r-boundary (1000 % 8 == 0)
#pragma unroll
  for (int u = tid; u < 1536; u += 256) {
    int c2 = u >> 4, ch = u & 15;
    int iidx0 = m0 + ch * 8;
    int r = iidx0 / 1000, n0 = iidx0 - r * 1000;
    *(uint4*)(h2t + (size_t)(r * 96 + c2) * 1024 + n0) = *(const uint4*)&Ts[c2 * 136 + ch * 8];
  }
}

// ============================================================
// prep: f32 -> bf16 conversions + W1/b1 moment stats + W2 split + cw pack
// ============================================================
__launch_bounds__(256)
__global__ void k_prep(const float* x, const float* fus_W,
                       const float* Wih0, const float* Whh0,
                       const float* Wih1, const float* Whh1,
                       const float* gcn_W1, const float* gcn_b1,
                       const float* gcn_W2, const float* ln1g, const float* ln1b,
                       u16* xbf, u16* fusWbf, u16* Wih0b, u16* Whh0b, u16* Wih1b, u16* Whh1b,
                       u16* W2s, float4* cwpk, float* consts)
{
  long o = (long)blockIdx.x * 256 + threadIdx.x;
  if (o < 384000) xbf[o] = f2bf(x[o]);
  else if ((o -= 384000) < 32000) fusWbf[o] = f2bf(fus_W[o]);
  else if ((o -= 32000) < 55296)  Wih0b[o] = f2bf(Wih0[o]);
  else if ((o -= 55296) < 110592) Whh0b[o] = f2bf(Whh0[o]);
  else if ((o -= 110592) < 110592) Wih1b[o] = f2bf(Wih1[o]);
  else if ((o -= 110592) < 110592) Whh1b[o] = f2bf(Whh1[o]);
  else if ((o -= 110592) < 9216) {
    int c2 = (int)o / 96, c = (int)o - c2 * 96;
    float wv = gcn_W2[c * 96 + c2];
    u16 hi = f2bf(wv);
    u16 lo = f2bf(wv - bf2f(hi));
    W2s[c2 * 192 + c] = hi;
    W2s[c2 * 192 + 96 + c] = lo;
  }
  else if ((o -= 9216) < 96) {
    int c = (int)o;
    float4 cw;
    cw.x = gcn_W1[c]; cw.y = gcn_b1[c]; cw.z = ln1g[c]; cw.w = ln1b[c];
    cwpk[c] = cw;
  }
  if (blockIdx.x == 0 && threadIdx.x == 0) {
    float sw = 0, sb = 0, sww = 0, swb = 0, sbb = 0;
    for (int c = 0; c < 96; c++) {
      float wv = gcn_W1[c], b = gcn_b1[c];
      sw += wv; sb += b; sww += wv * wv; swb += wv * b; sbb += b * b;
    }
    float P = sw / 96.f, Q = sb / 96.f;
    consts[0] = P; consts[1] = Q;
    consts[2] = sww / 96.f - P * P;
    consts[3] = swb / 96.f - P * Q;
    consts[4] = sbb / 96.f - Q * Q;
  }
}

// zero-fill: h2t K-pad columns (1000..1023) + score buffer
__launch_bounds__(256)
__global__ void k_zero(u16* __restrict__ h2t, float* __restrict__ score)
{
  int idx = blockIdx.x * 256 + threadIdx.x;
  if (idx < 110592) {
    int row = idx / 3, p = idx - row * 3;
    *(uint4*)(h2t + (size_t)row * 1024 + 1000 + p * 8) = make_uint4(0, 0, 0, 0);
  } else if ((idx -= 110592) < 32000) {
    score[idx] = 0.f;
  }
}

// fc1W (192x192 f32) -> split-bf16 B' (192 x 576): [wh | wl | wh]
__launch_bounds__(256)
__global__ void k_w1split(const float* __restrict__ fc1W, u16* __restrict__ w1s)
{
  int idx = blockIdx.x * 256 + threadIdx.x;
  if (idx >= 192 * 192) return;
  int n = idx / 192, k = idx - n * 192;
  float w = fc1W[idx];
  u16 hi = f2bf(w);
  u16 lo = f2bf(w - bf2f(hi));
  w1s[(size_t)n * 576 + k]       = hi;
  w1s[(size_t)n * 576 + 192 + k] = lo;
  w1s[(size_t)n * 576 + 384 + k] = hi;
}

// ============================================================
// per-row: Aadp softmax row + the 3 candidate graphs (bf16) + row sums
// ============================================================
__launch_bounds__(256)
__global__ void k_adjrow(const float* __restrict__ A, const float* __restrict__ FSP,
                         const float* __restrict__ DSP, const float* __restrict__ E1,
                         const float* __restrict__ E2,
                         const float* beta1, const float* beta2,
                         u16* __restrict__ G, float* __restrict__ rowsums)
{
  __shared__ float z[1000];
  __shared__ float red[256];
  const int n = blockIdx.x, tid = threadIdx.x;

  float e1r[10];
#pragma unroll
  for (int d = 0; d < 10; d++) e1r[d] = E1[n * 10 + d];

  float lmax = -1e30f;
  for (int m = tid; m < 1000; m += 256) {
    float s = 0;
#pragma unroll
    for (int d = 0; d < 10; d++) s += e1r[d] * E2[m * 10 + d];
    s = fmaxf(s, 0.f);
    z[m] = s;
    lmax = fmaxf(lmax, s);
  }
  red[tid] = lmax; __syncthreads();
  for (int st = 128; st > 0; st >>= 1) { if (tid < st) red[tid] = fmaxf(red[tid], red[tid + st]); __syncthreads(); }
  const float mx = red[0]; __syncthreads();

  float lsum = 0;
  for (int m = tid; m < 1000; m += 256) { float e = __expf(z[m] - mx); z[m] = e; lsum += e; }
  red[tid] = lsum; __syncthreads();
  for (int st = 128; st > 0; st >>= 1) { if (tid < st) red[tid] += red[tid + st]; __syncthreads(); }
  const float inv = 1.f / red[0]; __syncthreads();

  const float w1 = sigm(beta1[0]);
  const float w2 = sigm(beta2[0]);
  float s0 = 0, s1 = 0, s2 = 0;
  for (int m = tid; m < 1000; m += 256) {
    float aadp = z[m] * inv;
    float a = A[n * 1000 + m], f = FSP[n * 1000 + m], dd = DSP[n * 1000 + m];
    float g0 = 0.5f * a + 0.5f * aadp;
    float g1 = w1 * a + (1.f - w1) * f;
    float g2 = w2 * a + (1.f - w2) * dd;
    G[0 * 1000000 + n * 1000 + m] = f2bf(g0);
    G[1 * 1000000 + n * 1000 + m] = f2bf(g1);
    G[2 * 1000000 + n * 1000 + m] = f2bf(g2);
    s0 += g0; s1 += g1; s2 += g2;
  }
  red[tid] = s0; __syncthreads();
  for (int st = 128; st > 0; st >>= 1) { if (tid < st) red[tid] += red[tid + st]; __syncthreads(); }
  if (tid == 0) rowsums[n] = red[0];
  __syncthreads();
  red[tid] = s1; __syncthreads();
  for (int st = 128; st > 0; st >>= 1) { if (tid < st) red[tid] += red[tid + st]; __syncthreads(); }
  if (tid == 0) rowsums[1000 + n] = red[0];
  __syncthreads();
  red[tid] = s2; __syncthreads();
  for (int st = 128; st > 0; st >>= 1) { if (tid < st) red[tid] += red[tid + st]; __syncthreads(); }
  if (tid == 0) rowsums[2000 + n] = red[0];
}

// sc[k] = mean_n( sum_a tanh(P[k,n,a]+fus_b[a]) * fus_v[a] )
__launch_bounds__(256)
__global__ void k_sc(const float* __restrict__ P, const float* fus_b, const float* fus_v, float* sc)
{
  __shared__ float red[256];
  const int k = blockIdx.x, tid = threadIdx.x;
  float local = 0;
  for (int n = tid; n < 1000; n += 256) {
    const float* p = P + (size_t)(k * 1000 + n) * 32;
    float s = 0;
#pragma unroll
    for (int a = 0; a < 32; a++) s += tanhf(p[a] + fus_b[a]) * fus_v[a];
    local += s;
  }
  red[tid] = local; __syncthreads();
  for (int st = 128; st > 0; st >>= 1) { if (tid < st) red[tid] += red[tid + st]; __syncthreads(); }
  if (tid == 0) sc[k] = red[0] * (1.f / 1000.f);
}

__launch_bounds__(256)
__global__ void k_alpha(const float* sc, const float* rowsums, float* alpha_out, float* dinv)
{
  __shared__ float al[3];
  const int tid = threadIdx.x;
  if (tid == 0) {
    float m = fmaxf(sc[0], fmaxf(sc[1], sc[2]));
    float e0 = __expf(sc[0] - m), e1 = __expf(sc[1] - m), e2 = __expf(sc[2] - m);
    float inv = 1.f / (e0 + e1 + e2);
    al[0] = e0 * inv; al[1] = e1 * inv; al[2] = e2 * inv;
    alpha_out[0] = al[0]; alpha_out[1] = al[1]; alpha_out[2] = al[2];
  }
  __syncthreads();
  const float a0 = al[0], a1 = al[1], a2 = al[2];
  for (int n = tid; n < 1000; n += 256) {
    float d = a0 * rowsums[n] + a1 * rowsums[1000 + n] + a2 * rowsums[2000 + n] + 1.0f;
    dinv[n] = rsqrtf(fmaxf(d, 1e-12f));
  }
}

// S_hat -> Sbf with 1024 K-pad stride (pad cols zeroed)
__launch_bounds__(256)
__global__ void k_shat(const u16* __restrict__ G, const float* alpha, const float* dinv,
                       u16* __restrict__ S)
{
  int idx = blockIdx.x * 256 + threadIdx.x;
  if (idx >= 1024000) return;
  int i = idx >> 10, j = idx & 1023;
  u16 val = 0;
  if (j < 1000) {
    const float a0 = alpha[0], a1 = alpha[1], a2 = alpha[2];
    int g = i * 1000 + j;
    float mg = a0 * bf2f(G[g]) + a1 * bf2f(G[1000000 + g]) + a2 * bf2f(G[2000000 + g]);
    if (i == j) mg += 1.0f;
    val = f2bf(mg * dinv[i] * dinv[j]);
  }
  S[(size_t)i * 1024 + j] = val;
}

// In-place LN2 over 96 ch on g-layout buffer
__launch_bounds__(256)
__global__ void k_ln2g(u16* __restrict__ g, const float* __restrict__ b2,
                       const float* __restrict__ g2, const float* __restrict__ be2)
{
  const int i = blockIdx.x * 256 + threadIdx.x;
  if (i >= 384000) return;
  u16* row = g + (size_t)i * 96;

  uint4 raw[12];
#pragma unroll
  for (int t = 0; t < 12; t++) raw[t] = *(const uint4*)((const u16*)row + t * 8);

  float s = 0, ss = 0;
#pragma unroll
  for (int t = 0; t < 12; t++) {
    const u16* ch = (const u16*)&raw[t];
#pragma unroll
    for (int e = 0; e < 8; e++) {
      float v = bf2f(ch[e]) + b2[t * 8 + e];
      s += v; ss += v * v;
    }
  }
  const float mean = s * (1.f / 96.f);
  const float var  = ss * (1.f / 96.f) - mean * mean;
  const float isd  = rsqrtf(var + 1e-5f);

#pragma unroll
  for (int t = 0; t < 12; t++) {
    const u16* ch = (const u16*)&raw[t];
#pragma unroll
    for (int p = 0; p < 2; p++) {
      int c0 = t * 8 + p * 4;
      u32 w0 = f2bf((bf2f(ch[p * 4 + 0]) + b2[c0 + 0] - mean) * isd * g2[c0 + 0] + be2[c0 + 0]);
      u32 w1 = f2bf((bf2f(ch[p * 4 + 1]) + b2[c0 + 1] - mean) * isd * g2[c0 + 1] + be2[c0 + 1]);
      u32 w2 = f2bf((bf2f(ch[p * 4 + 2]) + b2[c0 + 2] - mean) * isd * g2[c0 + 2] + be2[c0 + 2]);
      u32 w3 = f2bf((bf2f(ch[p * 4 + 3]) + b2[c0 + 3] - mean) * isd * g2[c0 + 3] + be2[c0 + 3]);
      ((u32*)row)[t * 4 + p * 2 + 0] = (w0 | (w1 << 16));
      ((u32*)row)[t * 4 + p * 2 + 1] = (w2 | (w3 << 16));
    }
  }
}

// ctx = Nv/L, split to hi/lo bf16, pack A' rows [ch | ch | cl] (K=576)
__launch_bounds__(256)
__global__ void k_ctxsplit(const float* __restrict__ Nv, const float* __restrict__ Lbuf,
                           u16* __restrict__ ctxs)
{
  const int i = blockIdx.x * 256 + threadIdx.x;
  if (i >= 32000 * 192) return;
  const int q = i / 192, c = i - q * 192;
  float v = Nv[i] / Lbuf[q];
  u16 hi = f2bf(v);
  u16 lo = f2bf(v - bf2f(hi));
  u16* row = ctxs + (size_t)q * 576;
  row[c] = hi; row[192 + c] = hi; row[384 + c] = lo;
}

// fc2: LDS-staged tiny GEMM + transposed store
__launch_bounds__(192)
__global__ void k_fc2(const float* __restrict__ hfc, const float* __restrict__ fc2W,
                      const float* __restrict__ fc2b, float* __restrict__ out)
{
  __shared__ float w2S[12][193];
  __shared__ float hS[16][193];
  const int tid = threadIdx.x;
  const int q0 = blockIdx.x * 16;
  for (int idx = tid; idx < 12 * 192; idx += 192) {
    int o = idx / 192, k = idx - o * 192;
    w2S[o][k] = fc2W[idx];
  }
  for (int idx = tid; idx < 16 * 192; idx += 192) {
    int qq = idx / 192, k = idx - qq * 192;
    hS[qq][k] = hfc[(size_t)(q0 + qq) * 192 + k];
  }
  __syncthreads();
  const int qq = tid / 12, o = tid - qq * 12;
  float acc = fc2b[o];
#pragma unroll 8
  for (int k = 0; k < 192; k++) acc += hS[qq][k] * w2S[o][k];
  const int q = q0 + qq;
  const int b = q / 1000, node = q - b * 1000;
  out[(size_t)b * 12000 + o * 1000 + node] = acc;
}

// ============================================================
extern "C" void kernel_launch(void* const* d_in, const int* in_sizes, int n_in,
                              void* d_out, int out_size, void* d_ws, size_t ws_size,
                              hipStream_t stream)
{
  const float* x     = (const float*)d_in[0];
  const float* A     = (const float*)d_in[1];
  const float* FSP   = (const float*)d_in[2];
  const float* DSP   = (const float*)d_in[3];
  const float* E1    = (const float*)d_in[4];
  const float* E2    = (const float*)d_in[5];
  const float* fus_W = (const float*)d_in[6];
  const float* fus_b = (const float*)d_in[7];
  const float* fus_v = (const float*)d_in[8];
  const float* beta1 = (const float*)d_in[9];
  const float* beta2 = (const float*)d_in[10];
  const float* gcn_W1= (const float*)d_in[11];
  const float* gcn_b1= (const float*)d_in[12];
  const float* ln1g  = (const float*)d_in[13];
  const float* ln1b  = (const float*)d_in[14];
  const float* gcn_W2= (const float*)d_in[15];
  const float* gcn_b2= (const float*)d_in[16];
  const float* ln2g  = (const float*)d_in[17];
  const float* ln2b  = (const float*)d_in[18];
  const float* Wih0  = (const float*)d_in[19];
  const float* Whh0  = (const float*)d_in[20];
  const float* bih0  = (const float*)d_in[21];
  const float* bhh0  = (const float*)d_in[22];
  const float* Wih1  = (const float*)d_in[23];
  const float* Whh1  = (const float*)d_in[24];
  const float* bih1  = (const float*)d_in[25];
  const float* bhh1  = (const float*)d_in[26];
  const float* att_w = (const float*)d_in[27];
  const float* fc1W  = (const float*)d_in[28];
  const float* fc1b  = (const float*)d_in[29];
  const float* fc2W  = (const float*)d_in[30];
  const float* fc2b  = (const float*)d_in[31];
  float* out = (float*)d_out;

  char* w = (char*)d_ws;
  auto alloc = [&](size_t bytes) -> char* {
    char* p = w;
    w += (bytes + 255) & ~(size_t)255;
    return p;
  };

  float* consts  = (float*)alloc(8 * 4);
  float* scp     = (float*)alloc(3 * 4);
  float* alphap  = (float*)alloc(3 * 4);
  float* rowsums = (float*)alloc(3000 * 4);
  float* dinvp   = (float*)alloc(1000 * 4);
  u16*   Gbuf    = (u16*)alloc((size_t)3000000 * 2);
  u16*   Sbf     = (u16*)alloc((size_t)1024 * 1024 * 2);
  u16*   xbf     = (u16*)alloc((size_t)384000 * 2);
  u16*   fusWbf  = (u16*)alloc((size_t)32000 * 2);
  u16*   Wih0b   = (u16*)alloc((size_t)55296 * 2);
  u16*   Whh0b   = (u16*)alloc((size_t)110592 * 2);
  u16*   Wih1b   = (u16*)alloc((size_t)110592 * 2);
  u16*   Whh1b   = (u16*)alloc((size_t)110592 * 2);
  u16*   w1s     = (u16*)alloc((size_t)192 * 576 * 2);
  u16*   W2s     = (u16*)alloc((size_t)96 * 192 * 2);
  float4* cwpk   = (float4*)alloc((size_t)96 * 16);
  float* Pbuf    = (float*)alloc((size_t)96000 * 4);
  float* yt      = (float*)alloc((size_t)384000 * 4);
  u16*   h2t     = (u16*)alloc((size_t)36864 * 1024 * 2);  // 75.5 MB; states/FC alias later
  u16*   Gg      = (u16*)alloc((size_t)36864000 * 2);      // 73.7 MB
  float* Nv      = (float*)alloc((size_t)6144000 * 4);
  float* Mbuf    = (float*)alloc((size_t)32000 * 4);
  float* Lbuf    = (float*)alloc((size_t)32000 * 4);
  float* score   = (float*)alloc((size_t)32000 * 4);

  // GRU state double-buffers alias the h2t region (dead after k_bigemm)
  u16* h0buf[2] = { h2t,                    h2t + (size_t)6144000 };
  u16* h1buf[2] = { h2t + (size_t)12288000, h2t + (size_t)18432000 };
  // FC-head aliases (states dead after GRU loop)
  u16*   ctxs = h2t;
  float* hfc  = (float*)(h2t + (size_t)18432000);

  k_prep<<<3174, 256, 0, stream>>>(x, fus_W, Wih0, Whh0, Wih1, Whh1, gcn_W1, gcn_b1,
                                   gcn_W2, ln1g, ln1b,
                                   xbf, fusWbf, Wih0b, Whh0b, Wih1b, Whh1b, W2s, cwpk, consts);
  k_w1split<<<144, 256, 0, stream>>>(fc1W, w1s);
  k_zero<<<557, 256, 0, stream>>>(h2t, score);
  k_adjrow<<<1000, 256, 0, stream>>>(A, FSP, DSP, E1, E2, beta1, beta2, Gbuf, rowsums);
  gemm_nt<0><<<dim3(1, 24), 256, 0, stream>>>(Gbuf, 1000, fusWbf, 1000, Pbuf, 32, 3000, 32, 1000, nullptr);
  k_sc<<<3, 256, 0, stream>>>(Pbuf, fus_b, fus_v, scp);
  k_alpha<<<1, 256, 0, stream>>>(scp, rowsums, alphap, dinvp);
  k_shat<<<4000, 256, 0, stream>>>(Gbuf, alphap, dinvp, Sbf);
  // yt[m, r] = sum_n S[m,n] * x[r,n]
  gemm_nt<0><<<dim3(6, 8), 256, 0, stream>>>(Sbf, 1024, xbf, 1000, yt, 384, 1000, 384, 1000, nullptr);
  // h2t = Hln @ W2 (LN1 fused, LDS-transposed coalesced stores)
  k_h2gemm<<<3000, 256, 0, stream>>>(yt, cwpk, W2s, consts, h2t);
  // Gg = S @ h2t^T  (73.7 GFLOP)
  k_bigemm<<<2304, 256, 0, stream>>>(Sbf, h2t, Gg);
  k_ln2g<<<1500, 256, 0, stream>>>(Gg, gcn_b2, ln2g, ln2b);

  for (int t = 0; t < 12; ++t) {
    u16* h0in  = h0buf[t & 1];
    u16* h0out = h0buf[(t & 1) ^ 1];
    u16* h1in  = h1buf[t & 1];
    u16* h1out = h1buf[(t & 1) ^ 1];
    k_gru<96, false><<<dim3(3, 250), 256, 0, stream>>>(
        Gg + t * 96, 1152, Wih0b, h0in, Whh0b, bih0, bhh0, h0out, nullptr, nullptr, t == 0);
    k_gru<192, true><<<dim3(3, 250), 256, 0, stream>>>(
        h0out, 192, Wih1b, h1in, Whh1b, bih1, bhh1, h1out, att_w, score, t == 0);
    k_pool<<<32000, 192, 0, stream>>>(h1out, score, Mbuf, Lbuf, Nv, t == 0);
  }

  // FC head
  k_ctxsplit<<<24000, 256, 0, stream>>>(Nv, Lbuf, ctxs);
  gemm_nt<3><<<dim3(3, 250), 256, 0, stream>>>(ctxs, 576, w1s, 576, hfc, 192, 32000, 192, 576, fc1b);
  k_fc2<<<2000, 192, 0, stream>>>(hfc, fc2W, fc2b, out);
}

// Round 8
// 1651.302 us; speedup vs baseline: 2.3916x; 1.2873x over previous
//
#include <hip/hip_runtime.h>

typedef unsigned short u16;
typedef unsigned int u32;
typedef __attribute__((ext_vector_type(8))) short short8;   // 8 x bf16 (4 VGPRs)
typedef __attribute__((ext_vector_type(4))) float float4v;  // 4 x f32

#define DEV static __device__ __forceinline__

DEV float bf2f(u16 u) { u32 x = ((u32)u) << 16; float f; __builtin_memcpy(&f, &x, 4); return f; }
DEV u16 f2bf(float f) {
  u32 u; __builtin_memcpy(&u, &f, 4);
  u = (u + 0x7fffu + ((u >> 16) & 1u)) >> 16;
  return (u16)u;
}
DEV float sigm(float x) { return 1.f / (1.f + __expf(-x)); }

// async global->LDS, 16B per lane; LDS dest = wave-uniform base + lane*16
DEV void gl16(const u16* g, u16* l) {
  __builtin_amdgcn_global_load_lds(
      (const __attribute__((address_space(1))) void*)g,
      (__attribute__((address_space(3))) void*)l, 16, 0, 0);
}

// ============================================================
// Generic GEMM (small cases): C[M,N] = A[M,K](bf16) * B[N,K](bf16 "NK")
// OMODE: 0 = f32 row-major, 3 = f32 + bias + tanh-GELU epilogue (fc1)
// ============================================================
template <int OMODE>
__launch_bounds__(256)
__global__ void gemm_nt(const u16* __restrict__ A, int lda,
                        const u16* __restrict__ B, int ldb,
                        void* __restrict__ Cp, int ldc,
                        int M, int N, int K,
                        const float* __restrict__ bias)
{
  constexpr int PK = 40;
  __shared__ u16 As[128 * PK];
  __shared__ u16 Bs[64 * PK];

  const int tid  = threadIdx.x;
  const int m0   = blockIdx.y * 128;
  const int n0   = blockIdx.x * 64;
  const int wid  = tid >> 6;
  const int lane = tid & 63;
  const int l15  = lane & 15;
  const int quad = lane >> 4;
  const int wm   = (wid >> 1) * 64;
  const int wn   = (wid & 1) * 32;

  float4v acc[4][2];
  const float4v fz = {0.f, 0.f, 0.f, 0.f};
#pragma unroll
  for (int i = 0; i < 4; i++)
#pragma unroll
    for (int j = 0; j < 2; j++) acc[i][j] = fz;

  const int arow = tid >> 2;
  const int akc  = tid & 3;

  const int kt_count = (K + 31) / 32;
  for (int kt = 0; kt < kt_count; ++kt) {
    const int k0 = kt * 32 + akc * 8;
    const bool kok = (k0 < K);
    uint4 av0 = make_uint4(0, 0, 0, 0), av1 = av0, bv = av0;
    int ra = m0 + arow;
    if (kok && ra < M)        av0 = *(const uint4*)(A + (size_t)ra * lda + k0);
    if (kok && ra + 64 < M)   av1 = *(const uint4*)(A + (size_t)(ra + 64) * lda + k0);
    int rb = n0 + arow;
    if (kok && rb < N)        bv  = *(const uint4*)(B + (size_t)rb * ldb + k0);

    __syncthreads();
    *(uint4*)&As[arow * PK + akc * 8]        = av0;
    *(uint4*)&As[(arow + 64) * PK + akc * 8] = av1;
    *(uint4*)&Bs[arow * PK + akc * 8]        = bv;
    __syncthreads();

    short8 af[4], bfr[2];
#pragma unroll
    for (int i = 0; i < 4; i++)
      af[i] = *(const short8*)&As[(wm + i * 16 + l15) * PK + quad * 8];
#pragma unroll
    for (int j = 0; j < 2; j++)
      bfr[j] = *(const short8*)&Bs[(wn + j * 16 + l15) * PK + quad * 8];
#pragma unroll
    for (int i = 0; i < 4; i++)
#pragma unroll
      for (int j = 0; j < 2; j++)
        acc[i][j] = __builtin_amdgcn_mfma_f32_16x16x32_bf16(af[i], bfr[j], acc[i][j], 0, 0, 0);
  }

#pragma unroll
  for (int i = 0; i < 4; i++)
#pragma unroll
    for (int j = 0; j < 2; j++)
#pragma unroll
      for (int e = 0; e < 4; e++) {
        int r = m0 + wm + i * 16 + quad * 4 + e;
        int c = n0 + wn + j * 16 + l15;
        if (r < M && c < N) {
          float v = acc[i][j][e];
          if (OMODE == 0) ((float*)Cp)[(size_t)r * ldc + c] = v;
          else {
            float a = v + bias[c];
            float t = tanhf(0.7978845608028654f * (a + 0.044715f * a * a * a));
            ((float*)Cp)[(size_t)r * ldc + c] = 0.5f * a * (1.f + t);
          }
        }
      }
}

// ============================================================
// Big graph-conv GEMM: Gg = S(1000x1024) @ h2t(36864x1024)^T
// 128x128x32, global_load_lds(16B), XCD swizzle, g-layout scatter.
// ============================================================
__launch_bounds__(256)
__global__ void k_bigemm(const u16* __restrict__ A,
                         const u16* __restrict__ B,
                         u16* __restrict__ Gg)
{
  __shared__ u16 As[128 * 32];
  __shared__ u16 Bs[128 * 32];
  const int tid  = threadIdx.x;
  const int bid  = blockIdx.x;
  const int xcd  = bid & 7;
  const int jj   = bid >> 3;
  const int m0   = (jj & 7) * 128;
  const int n0   = (xcd + 8 * (jj >> 3)) * 128;

  const int wid  = tid >> 6;
  const int lane = tid & 63;
  const int l15  = lane & 15;
  const int quad = lane >> 4;
  const int wm   = (wid >> 1) * 64;
  const int wn   = (wid & 1) * 64;

  const int srow = wid * 16 + (lane >> 2);
  const int skc  = (lane & 3) * 8;

  const u16* agp0 = A + (size_t)(m0 + srow) * 1024 + skc;
  const u16* agp1 = agp0 + (size_t)64 * 1024;
  const u16* bgp0 = B + (size_t)(n0 + srow) * 1024 + skc;
  const u16* bgp1 = bgp0 + (size_t)64 * 1024;
  u16* asl0 = &As[(wid * 16) * 32];
  u16* asl1 = &As[(64 + wid * 16) * 32];
  u16* bsl0 = &Bs[(wid * 16) * 32];
  u16* bsl1 = &Bs[(64 + wid * 16) * 32];

  float4v acc[4][4];
  const float4v fz = {0.f, 0.f, 0.f, 0.f};
#pragma unroll
  for (int i = 0; i < 4; i++)
#pragma unroll
    for (int j = 0; j < 4; j++) acc[i][j] = fz;

  for (int kt = 0; kt < 32; ++kt) {
    const int ko = kt * 32;
    gl16(agp0 + ko, asl0);
    gl16(agp1 + ko, asl1);
    gl16(bgp0 + ko, bsl0);
    gl16(bgp1 + ko, bsl1);
    __syncthreads();
    short8 af[4], bf[4];
#pragma unroll
    for (int i = 0; i < 4; i++)
      af[i] = *(const short8*)&As[(wm + i * 16 + l15) * 32 + quad * 8];
#pragma unroll
    for (int j = 0; j < 4; j++)
      bf[j] = *(const short8*)&Bs[(wn + j * 16 + l15) * 32 + quad * 8];
#pragma unroll
    for (int i = 0; i < 4; i++)
#pragma unroll
      for (int j = 0; j < 4; j++)
        acc[i][j] = __builtin_amdgcn_mfma_f32_16x16x32_bf16(af[i], bf[j], acc[i][j], 0, 0, 0);
    __syncthreads();
  }

#pragma unroll
  for (int i = 0; i < 4; i++)
#pragma unroll
    for (int j = 0; j < 4; j++)
#pragma unroll
      for (int e = 0; e < 4; e++) {
        int r = m0 + wm + i * 16 + quad * 4 + e;
        if (r < 1000) {
          int c = n0 + wn + j * 16 + l15;
          int rs = c / 96, cc = c - rs * 96;
          Gg[(size_t)rs * 96000 + (size_t)r * 96 + cc] = f2bf(acc[i][j][e]);
        }
      }
}

// ============================================================
// Fused GRU step, 6-way N split: BM=128, 32 cols per gate per block.
// acc [2][2] x 4 sets = 64 VGPRs -> ~4 waves/SIMD occupancy.
// POOL: partial attention scores via butterfly + atomicAdd.
// ============================================================
template <int KX, bool POOL>
__launch_bounds__(256)
__global__ void k_gru(const u16* __restrict__ Xin, int ldx,
                      const u16* __restrict__ Win,
                      const u16* __restrict__ Hin,
                      const u16* __restrict__ Whh,
                      const float* __restrict__ bih, const float* __restrict__ bhh,
                      u16* __restrict__ Hout,
                      const float* __restrict__ att_w, float* __restrict__ score,
                      int t0)
{
  __shared__ u16 As[128 * 32];
  __shared__ u16 Bs[96 * 32];
  const int tid  = threadIdx.x;
  const int m0   = blockIdx.y * 128;
  const int c0   = blockIdx.x * 32;      // 32 cols per gate
  const int wid  = tid >> 6;
  const int lane = tid & 63;
  const int l15  = lane & 15;
  const int quad = lane >> 4;
  const int wm   = wid * 32;             // 4 waves x 32 rows
  const int srow = lane >> 2;            // 0..15
  const int skc  = (lane & 3) * 8;

  float4v aR[2][2], aZ[2][2], aXN[2][2], aHN[2][2];
  const float4v fz = {0.f, 0.f, 0.f, 0.f};
#pragma unroll
  for (int i = 0; i < 2; i++)
#pragma unroll
    for (int j = 0; j < 2; j++) { aR[i][j] = fz; aZ[i][j] = fz; aXN[i][j] = fz; aHN[i][j] = fz; }

  // B staging row mapping: Bs rows 0..31 = R cols, 32..63 = Z, 64..95 = N
  const int br0   = wid * 16 + srow;                    // 0..63
  const int grow0 = (br0 >> 5) * 192 + c0 + (br0 & 31); // gate 0/1
  const int br1   = 64 + wid * 16 + srow;               // 64..95 (wid<2)
  const int grow1 = 384 + c0 + (br1 & 31);              // gate 2
  u16* asl0 = &As[(wid * 16) * 32];
  u16* asl1 = &As[(64 + wid * 16) * 32];
  u16* bsl0 = &Bs[(wid * 16) * 32];
  u16* bsl1 = &Bs[(64 + wid * 16) * 32];

  // ---- phase X: acc += X @ Win^T ----
  {
    const u16* ax0 = Xin + (size_t)(m0 + wid * 16 + srow) * ldx + skc;
    const u16* ax1 = Xin + (size_t)(m0 + 64 + wid * 16 + srow) * ldx + skc;
    const u16* bx0 = Win + (size_t)grow0 * KX + skc;
    const u16* bx1 = Win + (size_t)grow1 * KX + skc;
#pragma unroll
    for (int kt = 0; kt < KX / 32; ++kt) {
      const int ko = kt * 32;
      gl16(ax0 + ko, asl0); gl16(ax1 + ko, asl1);
      gl16(bx0 + ko, bsl0);
      if (wid < 2) gl16(bx1 + ko, bsl1);
      __syncthreads();
      short8 af[2], bR[2], bZ[2], bN[2];
#pragma unroll
      for (int i = 0; i < 2; i++)
        af[i] = *(const short8*)&As[(wm + i * 16 + l15) * 32 + quad * 8];
#pragma unroll
      for (int j = 0; j < 2; j++) {
        bR[j] = *(const short8*)&Bs[(j * 16 + l15) * 32 + quad * 8];
        bZ[j] = *(const short8*)&Bs[(32 + j * 16 + l15) * 32 + quad * 8];
        bN[j] = *(const short8*)&Bs[(64 + j * 16 + l15) * 32 + quad * 8];
      }
#pragma unroll
      for (int i = 0; i < 2; i++)
#pragma unroll
        for (int j = 0; j < 2; j++) {
          aR[i][j]  = __builtin_amdgcn_mfma_f32_16x16x32_bf16(af[i], bR[j], aR[i][j], 0, 0, 0);
          aZ[i][j]  = __builtin_amdgcn_mfma_f32_16x16x32_bf16(af[i], bZ[j], aZ[i][j], 0, 0, 0);
          aXN[i][j] = __builtin_amdgcn_mfma_f32_16x16x32_bf16(af[i], bN[j], aXN[i][j], 0, 0, 0);
        }
      __syncthreads();
    }
  }
  // ---- phase H: acc += Hin @ Whh^T ----
  if (!t0) {
    const u16* ah0 = Hin + (size_t)(m0 + wid * 16 + srow) * 192 + skc;
    const u16* ah1 = Hin + (size_t)(m0 + 64 + wid * 16 + srow) * 192 + skc;
    const u16* bh0 = Whh + (size_t)grow0 * 192 + skc;
    const u16* bh1 = Whh + (size_t)grow1 * 192 + skc;
#pragma unroll
    for (int kt = 0; kt < 6; ++kt) {
      const int ko = kt * 32;
      gl16(ah0 + ko, asl0); gl16(ah1 + ko, asl1);
      gl16(bh0 + ko, bsl0);
      if (wid < 2) gl16(bh1 + ko, bsl1);
      __syncthreads();
      short8 af[2], bR[2], bZ[2], bN[2];
#pragma unroll
      for (int i = 0; i < 2; i++)
        af[i] = *(const short8*)&As[(wm + i * 16 + l15) * 32 + quad * 8];
#pragma unroll
      for (int j = 0; j < 2; j++) {
        bR[j] = *(const short8*)&Bs[(j * 16 + l15) * 32 + quad * 8];
        bZ[j] = *(const short8*)&Bs[(32 + j * 16 + l15) * 32 + quad * 8];
        bN[j] = *(const short8*)&Bs[(64 + j * 16 + l15) * 32 + quad * 8];
      }
#pragma unroll
      for (int i = 0; i < 2; i++)
#pragma unroll
        for (int j = 0; j < 2; j++) {
          aR[i][j]  = __builtin_amdgcn_mfma_f32_16x16x32_bf16(af[i], bR[j], aR[i][j], 0, 0, 0);
          aZ[i][j]  = __builtin_amdgcn_mfma_f32_16x16x32_bf16(af[i], bZ[j], aZ[i][j], 0, 0, 0);
          aHN[i][j] = __builtin_amdgcn_mfma_f32_16x16x32_bf16(af[i], bN[j], aHN[i][j], 0, 0, 0);
        }
      __syncthreads();
    }
  }

  // ---- epilogue: gates + state write (+ pooling partials) ----
  float ps[2][4];
  if (POOL) {
#pragma unroll
    for (int i = 0; i < 2; i++)
#pragma unroll
      for (int e = 0; e < 4; e++) ps[i][e] = 0.f;
  }
#pragma unroll
  for (int j = 0; j < 2; ++j) {
    const int c = c0 + j * 16 + l15;
    const float brz = bih[c] + bhh[c];
    const float bzz = bih[192 + c] + bhh[192 + c];
    const float bxn = bih[384 + c];
    const float bhn = bhh[384 + c];
    const float aw  = POOL ? att_w[c] : 0.f;
#pragma unroll
    for (int i = 0; i < 2; ++i)
#pragma unroll
      for (int e = 0; e < 4; ++e) {
        const int row = m0 + wm + i * 16 + quad * 4 + e;
        float rg  = sigm(aR[i][j][e] + brz);
        float zg  = sigm(aZ[i][j][e] + bzz);
        float hnv = bhn + (t0 ? 0.f : aHN[i][j][e]);
        float ng  = tanhf(aXN[i][j][e] + bxn + rg * hnv);
        float hold = t0 ? 0.f : bf2f(Hin[(size_t)row * 192 + c]);
        float hnew = (1.f - zg) * ng + zg * hold;
        Hout[(size_t)row * 192 + c] = f2bf(hnew);
        if (POOL) ps[i][e] += hnew * aw;
      }
  }
  if (POOL) {
#pragma unroll
    for (int i = 0; i < 2; ++i)
#pragma unroll
      for (int e = 0; e < 4; ++e) {
        float v = ps[i][e];
        v += __shfl_xor(v, 1); v += __shfl_xor(v, 2);
        v += __shfl_xor(v, 4); v += __shfl_xor(v, 8);
        if (l15 == 0) atomicAdd(&score[m0 + wm + i * 16 + quad * 4 + e], v);
      }
  }
}

// online-softmax pooling: 8 q per 256-thread block, per-thread recompute of
// (Mn, so, wn) -- no broadcast chain. tid<8 owns the M/L/score writes.
__launch_bounds__(256)
__global__ void k_pool(const u16* __restrict__ H, float* __restrict__ score,
                       float* __restrict__ Mbuf, float* __restrict__ Lbuf,
                       float* __restrict__ Nv, int t0)
{
  const int base = blockIdx.x * 1536;   // 8 q * 192
  const int tid  = threadIdx.x;

  float prev[6], hnew[6], so[6], wn[6];
#pragma unroll
  for (int k = 0; k < 6; k++) {
    const int idx = base + tid + k * 256;
    const int q = idx / 192;
    const float s = score[q];
    hnew[k] = bf2f(H[idx]);
    if (t0) {
      so[k] = 0.f; wn[k] = 1.f; prev[k] = 0.f;
    } else {
      const float Mo = Mbuf[q];
      const float Mn = fmaxf(Mo, s);
      so[k] = __expf(Mo - Mn);
      wn[k] = __expf(s - Mn);
      prev[k] = Nv[idx];
    }
  }
  // per-q state update by the first 8 threads (after all reads above)
  float Mw = 0.f, Lw = 0.f;
  int qw = -1;
  if (tid < 8) {
    qw = blockIdx.x * 8 + tid;
    const float s = score[qw];
    if (t0) { Mw = s; Lw = 1.f; }
    else {
      const float Mo = Mbuf[qw];
      const float Mn = fmaxf(Mo, s);
      Mw = Mn;
      Lw = Lbuf[qw] * __expf(Mo - Mn) + __expf(s - Mn);
    }
  }
  __syncthreads();
  if (tid < 8) { Mbuf[qw] = Mw; Lbuf[qw] = Lw; score[qw] = 0.f; }
#pragma unroll
  for (int k = 0; k < 6; k++) {
    const int idx = base + tid + k * 256;
    Nv[idx] = prev[k] * so[k] + wn[k] * hnew[k];
  }
}

// ============================================================
// H2 GEMM: h2t[(r*96+c2)*1024+n] = Hln @ W2 (analytic LN1 in A-staging)
// Epilogue: LDS-transpose + coalesced dwordx4 stores along n.
// ============================================================
__launch_bounds__(256)
__global__ void k_h2gemm(const float* __restrict__ yt, const float4* __restrict__ cwpk,
                         const u16* __restrict__ W2s, const float* __restrict__ consts,
                         u16* __restrict__ h2t)
{
  constexpr int PK = 40;
  __shared__ u16 As[128 * PK];
  __shared__ u16 Bs[96 * PK];
  __shared__ u16 Ts[96 * 136];   // transpose staging, pitch 136 (16B-aligned rows)

  const int tid  = threadIdx.x;
  const int m0   = blockIdx.x * 128;
  const int wid  = tid >> 6;
  const int lane = tid & 63;
  const int l15  = lane & 15;
  const int quad = lane >> 4;
  const int wm   = (wid >> 1) * 64;
  const int wn   = (wid & 1) * 48;

  const float P = consts[0], Q = consts[1], VW = consts[2], CWB = consts[3], VB = consts[4];

  const int arow = tid >> 2;
  const int akc  = tid & 3;

  float yv[2], mu[2], iv[2];
#pragma unroll
  for (int rr = 0; rr < 2; rr++) {
    int i = m0 + arow + rr * 64;
    int r = i / 1000, n = i - r * 1000;
    float y = yt[n * 384 + r];
    yv[rr] = y;
    mu[rr] = y * P + Q;
    iv[rr] = rsqrtf(y * y * VW + 2.f * y * CWB + VB + 1e-5f);
  }

  float4v acc[4][3];
  const float4v fz = {0.f, 0.f, 0.f, 0.f};
#pragma unroll
  for (int i = 0; i < 4; i++)
#pragma unroll
    for (int j = 0; j < 3; j++) acc[i][j] = fz;

  uint4 asave[2][3];
  const bool has2 = (arow < 32);

  for (int kt = 0; kt < 6; ++kt) {
    const int k0 = kt * 32 + akc * 8;
    uint4 av[2];
    if (kt < 3) {
#pragma unroll
      for (int rr = 0; rr < 2; rr++) {
        u16 hb[8];
#pragma unroll
        for (int e = 0; e < 8; e++) {
          float4 cw = cwpk[k0 + e];
          float t = yv[rr] * cw.x + cw.y - mu[rr];
          float h = fmaxf(t * iv[rr] * cw.z + cw.w, 0.f);
          hb[e] = f2bf(h);
        }
        __builtin_memcpy(&av[rr], hb, 16);
        asave[rr][kt] = av[rr];
      }
    } else {
      av[0] = asave[0][kt - 3];
      av[1] = asave[1][kt - 3];
    }
    uint4 bv0 = *(const uint4*)(W2s + (size_t)arow * 192 + k0);
    uint4 bv1 = make_uint4(0, 0, 0, 0);
    if (has2) bv1 = *(const uint4*)(W2s + (size_t)(arow + 64) * 192 + k0);

    __syncthreads();
    *(uint4*)&As[arow * PK + akc * 8]        = av[0];
    *(uint4*)&As[(arow + 64) * PK + akc * 8] = av[1];
    *(uint4*)&Bs[arow * PK + akc * 8]        = bv0;
    if (has2) *(uint4*)&Bs[(arow + 64) * PK + akc * 8] = bv1;
    __syncthreads();

    short8 af[4], bfr[3];
#pragma unroll
    for (int i = 0; i < 4; i++)
      af[i] = *(const short8*)&As[(wm + i * 16 + l15) * PK + quad * 8];
#pragma unroll
    for (int j = 0; j < 3; j++)
      bfr[j] = *(const short8*)&Bs[(wn + j * 16 + l15) * PK + quad * 8];
#pragma unroll
    for (int i = 0; i < 4; i++)
#pragma unroll
      for (int j = 0; j < 3; j++)
        acc[i][j] = __builtin_amdgcn_mfma_f32_16x16x32_bf16(af[i], bfr[j], acc[i][j], 0, 0, 0);
  }

  // transpose tile into LDS: Ts[c2][row_local]
#pragma unroll
  for (int i = 0; i < 4; i++)
#pragma unroll
    for (int j = 0; j < 3; j++)
#pragma unroll
      for (int e = 0; e < 4; e++) {
        int rowl = wm + i * 16 + quad * 4 + e;
        int c2   = wn + j * 16 + l15;
        Ts[c2 * 136 + rowl] = f2bf(acc[i][j][e]);
      }
  __syncthreads();
  // coalesced stores: 8-wide n-chunks never cross the r-boundary (1000 % 8 == 0)
#pragma unroll
  for (int u = tid; u < 1536; u += 256) {
    int c2 = u >> 4, ch = u & 15;
    int iidx0 = m0 + ch * 8;
    int r = iidx0 / 1000, n0 = iidx0 - r * 1000;
    *(uint4*)(h2t + (size_t)(r * 96 + c2) * 1024 + n0) = *(const uint4*)&Ts[c2 * 136 + ch * 8];
  }
}

// ============================================================
// prep: f32 -> bf16 conversions + W1/b1 moment stats + W2 split + cw pack
// ============================================================
__launch_bounds__(256)
__global__ void k_prep(const float* x, const float* fus_W,
                       const float* Wih0, const float* Whh0,
                       const float* Wih1, const float* Whh1,
                       const float* gcn_W1, const float* gcn_b1,
                       const float* gcn_W2, const float* ln1g, const float* ln1b,
                       u16* xbf, u16* fusWbf, u16* Wih0b, u16* Whh0b, u16* Wih1b, u16* Whh1b,
                       u16* W2s, float4* cwpk, float* consts)
{
  long o = (long)blockIdx.x * 256 + threadIdx.x;
  if (o < 384000) xbf[o] = f2bf(x[o]);
  else if ((o -= 384000) < 32000) fusWbf[o] = f2bf(fus_W[o]);
  else if ((o -= 32000) < 55296)  Wih0b[o] = f2bf(Wih0[o]);
  else if ((o -= 55296) < 110592) Whh0b[o] = f2bf(Whh0[o]);
  else if ((o -= 110592) < 110592) Wih1b[o] = f2bf(Wih1[o]);
  else if ((o -= 110592) < 110592) Whh1b[o] = f2bf(Whh1[o]);
  else if ((o -= 110592) < 9216) {
    int c2 = (int)o / 96, c = (int)o - c2 * 96;
    float wv = gcn_W2[c * 96 + c2];
    u16 hi = f2bf(wv);
    u16 lo = f2bf(wv - bf2f(hi));
    W2s[c2 * 192 + c] = hi;
    W2s[c2 * 192 + 96 + c] = lo;
  }
  else if ((o -= 9216) < 96) {
    int c = (int)o;
    float4 cw;
    cw.x = gcn_W1[c]; cw.y = gcn_b1[c]; cw.z = ln1g[c]; cw.w = ln1b[c];
    cwpk[c] = cw;
  }
  if (blockIdx.x == 0 && threadIdx.x == 0) {
    float sw = 0, sb = 0, sww = 0, swb = 0, sbb = 0;
    for (int c = 0; c < 96; c++) {
      float wv = gcn_W1[c], b = gcn_b1[c];
      sw += wv; sb += b; sww += wv * wv; swb += wv * b; sbb += b * b;
    }
    float P = sw / 96.f, Q = sb / 96.f;
    consts[0] = P; consts[1] = Q;
    consts[2] = sww / 96.f - P * P;
    consts[3] = swb / 96.f - P * Q;
    consts[4] = sbb / 96.f - Q * Q;
  }
}

// zero-fill: h2t K-pad columns (1000..1023) + score buffer
__launch_bounds__(256)
__global__ void k_zero(u16* __restrict__ h2t, float* __restrict__ score)
{
  int idx = blockIdx.x * 256 + threadIdx.x;
  if (idx < 110592) {
    int row = idx / 3, p = idx - row * 3;
    *(uint4*)(h2t + (size_t)row * 1024 + 1000 + p * 8) = make_uint4(0, 0, 0, 0);
  } else if ((idx -= 110592) < 32000) {
    score[idx] = 0.f;
  }
}

// fc1W (192x192 f32) -> split-bf16 B' (192 x 576): [wh | wl | wh]
__launch_bounds__(256)
__global__ void k_w1split(const float* __restrict__ fc1W, u16* __restrict__ w1s)
{
  int idx = blockIdx.x * 256 + threadIdx.x;
  if (idx >= 192 * 192) return;
  int n = idx / 192, k = idx - n * 192;
  float w = fc1W[idx];
  u16 hi = f2bf(w);
  u16 lo = f2bf(w - bf2f(hi));
  w1s[(size_t)n * 576 + k]       = hi;
  w1s[(size_t)n * 576 + 192 + k] = lo;
  w1s[(size_t)n * 576 + 384 + k] = hi;
}

// ============================================================
// per-row: Aadp softmax row + the 3 candidate graphs (bf16) + row sums
// ============================================================
__launch_bounds__(256)
__global__ void k_adjrow(const float* __restrict__ A, const float* __restrict__ FSP,
                         const float* __restrict__ DSP, const float* __restrict__ E1,
                         const float* __restrict__ E2,
                         const float* beta1, const float* beta2,
                         u16* __restrict__ G, float* __restrict__ rowsums)
{
  __shared__ float z[1000];
  __shared__ float red[256];
  const int n = blockIdx.x, tid = threadIdx.x;

  float e1r[10];
#pragma unroll
  for (int d = 0; d < 10; d++) e1r[d] = E1[n * 10 + d];

  float lmax = -1e30f;
  for (int m = tid; m < 1000; m += 256) {
    float s = 0;
#pragma unroll
    for (int d = 0; d < 10; d++) s += e1r[d] * E2[m * 10 + d];
    s = fmaxf(s, 0.f);
    z[m] = s;
    lmax = fmaxf(lmax, s);
  }
  red[tid] = lmax; __syncthreads();
  for (int st = 128; st > 0; st >>= 1) { if (tid < st) red[tid] = fmaxf(red[tid], red[tid + st]); __syncthreads(); }
  const float mx = red[0]; __syncthreads();

  float lsum = 0;
  for (int m = tid; m < 1000; m += 256) { float e = __expf(z[m] - mx); z[m] = e; lsum += e; }
  red[tid] = lsum; __syncthreads();
  for (int st = 128; st > 0; st >>= 1) { if (tid < st) red[tid] += red[tid + st]; __syncthreads(); }
  const float inv = 1.f / red[0]; __syncthreads();

  const float w1 = sigm(beta1[0]);
  const float w2 = sigm(beta2[0]);
  float s0 = 0, s1 = 0, s2 = 0;
  for (int m = tid; m < 1000; m += 256) {
    float aadp = z[m] * inv;
    float a = A[n * 1000 + m], f = FSP[n * 1000 + m], dd = DSP[n * 1000 + m];
    float g0 = 0.5f * a + 0.5f * aadp;
    float g1 = w1 * a + (1.f - w1) * f;
    float g2 = w2 * a + (1.f - w2) * dd;
    G[0 * 1000000 + n * 1000 + m] = f2bf(g0);
    G[1 * 1000000 + n * 1000 + m] = f2bf(g1);
    G[2 * 1000000 + n * 1000 + m] = f2bf(g2);
    s0 += g0; s1 += g1; s2 += g2;
  }
  red[tid] = s0; __syncthreads();
  for (int st = 128; st > 0; st >>= 1) { if (tid < st) red[tid] += red[tid + st]; __syncthreads(); }
  if (tid == 0) rowsums[n] = red[0];
  __syncthreads();
  red[tid] = s1; __syncthreads();
  for (int st = 128; st > 0; st >>= 1) { if (tid < st) red[tid] += red[tid + st]; __syncthreads(); }
  if (tid == 0) rowsums[1000 + n] = red[0];
  __syncthreads();
  red[tid] = s2; __syncthreads();
  for (int st = 128; st > 0; st >>= 1) { if (tid < st) red[tid] += red[tid + st]; __syncthreads(); }
  if (tid == 0) rowsums[2000 + n] = red[0];
}

// sc[k] = mean_n( sum_a tanh(P[k,n,a]+fus_b[a]) * fus_v[a] )
__launch_bounds__(256)
__global__ void k_sc(const float* __restrict__ P, const float* fus_b, const float* fus_v, float* sc)
{
  __shared__ float red[256];
  const int k = blockIdx.x, tid = threadIdx.x;
  float local = 0;
  for (int n = tid; n < 1000; n += 256) {
    const float* p = P + (size_t)(k * 1000 + n) * 32;
    float s = 0;
#pragma unroll
    for (int a = 0; a < 32; a++) s += tanhf(p[a] + fus_b[a]) * fus_v[a];
    local += s;
  }
  red[tid] = local; __syncthreads();
  for (int st = 128; st > 0; st >>= 1) { if (tid < st) red[tid] += red[tid + st]; __syncthreads(); }
  if (tid == 0) sc[k] = red[0] * (1.f / 1000.f);
}

__launch_bounds__(256)
__global__ void k_alpha(const float* sc, const float* rowsums, float* alpha_out, float* dinv)
{
  __shared__ float al[3];
  const int tid = threadIdx.x;
  if (tid == 0) {
    float m = fmaxf(sc[0], fmaxf(sc[1], sc[2]));
    float e0 = __expf(sc[0] - m), e1 = __expf(sc[1] - m), e2 = __expf(sc[2] - m);
    float inv = 1.f / (e0 + e1 + e2);
    al[0] = e0 * inv; al[1] = e1 * inv; al[2] = e2 * inv;
    alpha_out[0] = al[0]; alpha_out[1] = al[1]; alpha_out[2] = al[2];
  }
  __syncthreads();
  const float a0 = al[0], a1 = al[1], a2 = al[2];
  for (int n = tid; n < 1000; n += 256) {
    float d = a0 * rowsums[n] + a1 * rowsums[1000 + n] + a2 * rowsums[2000 + n] + 1.0f;
    dinv[n] = rsqrtf(fmaxf(d, 1e-12f));
  }
}

// S_hat -> Sbf with 1024 K-pad stride (pad cols zeroed)
__launch_bounds__(256)
__global__ void k_shat(const u16* __restrict__ G, const float* alpha, const float* dinv,
                       u16* __restrict__ S)
{
  int idx = blockIdx.x * 256 + threadIdx.x;
  if (idx >= 1024000) return;
  int i = idx >> 10, j = idx & 1023;
  u16 val = 0;
  if (j < 1000) {
    const float a0 = alpha[0], a1 = alpha[1], a2 = alpha[2];
    int g = i * 1000 + j;
    float mg = a0 * bf2f(G[g]) + a1 * bf2f(G[1000000 + g]) + a2 * bf2f(G[2000000 + g]);
    if (i == j) mg += 1.0f;
    val = f2bf(mg * dinv[i] * dinv[j]);
  }
  S[(size_t)i * 1024 + j] = val;
}

// In-place LN2 over 96 ch on g-layout buffer
__launch_bounds__(256)
__global__ void k_ln2g(u16* __restrict__ g, const float* __restrict__ b2,
                       const float* __restrict__ g2, const float* __restrict__ be2)
{
  const int i = blockIdx.x * 256 + threadIdx.x;
  if (i >= 384000) return;
  u16* row = g + (size_t)i * 96;

  uint4 raw[12];
#pragma unroll
  for (int t = 0; t < 12; t++) raw[t] = *(const uint4*)((const u16*)row + t * 8);

  float s = 0, ss = 0;
#pragma unroll
  for (int t = 0; t < 12; t++) {
    const u16* ch = (const u16*)&raw[t];
#pragma unroll
    for (int e = 0; e < 8; e++) {
      float v = bf2f(ch[e]) + b2[t * 8 + e];
      s += v; ss += v * v;
    }
  }
  const float mean = s * (1.f / 96.f);
  const float var  = ss * (1.f / 96.f) - mean * mean;
  const float isd  = rsqrtf(var + 1e-5f);

#pragma unroll
  for (int t = 0; t < 12; t++) {
    const u16* ch = (const u16*)&raw[t];
#pragma unroll
    for (int p = 0; p < 2; p++) {
      int c0 = t * 8 + p * 4;
      u32 w0 = f2bf((bf2f(ch[p * 4 + 0]) + b2[c0 + 0] - mean) * isd * g2[c0 + 0] + be2[c0 + 0]);
      u32 w1 = f2bf((bf2f(ch[p * 4 + 1]) + b2[c0 + 1] - mean) * isd * g2[c0 + 1] + be2[c0 + 1]);
      u32 w2 = f2bf((bf2f(ch[p * 4 + 2]) + b2[c0 + 2] - mean) * isd * g2[c0 + 2] + be2[c0 + 2]);
      u32 w3 = f2bf((bf2f(ch[p * 4 + 3]) + b2[c0 + 3] - mean) * isd * g2[c0 + 3] + be2[c0 + 3]);
      ((u32*)row)[t * 4 + p * 2 + 0] = (w0 | (w1 << 16));
      ((u32*)row)[t * 4 + p * 2 + 1] = (w2 | (w3 << 16));
    }
  }
}

// ctx = Nv/L, split to hi/lo bf16, pack A' rows [ch | ch | cl] (K=576)
__launch_bounds__(256)
__global__ void k_ctxsplit(const float* __restrict__ Nv, const float* __restrict__ Lbuf,
                           u16* __restrict__ ctxs)
{
  const int i = blockIdx.x * 256 + threadIdx.x;
  if (i >= 32000 * 192) return;
  const int q = i / 192, c = i - q * 192;
  float v = Nv[i] / Lbuf[q];
  u16 hi = f2bf(v);
  u16 lo = f2bf(v - bf2f(hi));
  u16* row = ctxs + (size_t)q * 576;
  row[c] = hi; row[192 + c] = hi; row[384 + c] = lo;
}

// fc2: LDS-staged tiny GEMM + transposed store
__launch_bounds__(192)
__global__ void k_fc2(const float* __restrict__ hfc, const float* __restrict__ fc2W,
                      const float* __restrict__ fc2b, float* __restrict__ out)
{
  __shared__ float w2S[12][193];
  __shared__ float hS[16][193];
  const int tid = threadIdx.x;
  const int q0 = blockIdx.x * 16;
  for (int idx = tid; idx < 12 * 192; idx += 192) {
    int o = idx / 192, k = idx - o * 192;
    w2S[o][k] = fc2W[idx];
  }
  for (int idx = tid; idx < 16 * 192; idx += 192) {
    int qq = idx / 192, k = idx - qq * 192;
    hS[qq][k] = hfc[(size_t)(q0 + qq) * 192 + k];
  }
  __syncthreads();
  const int qq = tid / 12, o = tid - qq * 12;
  float acc = fc2b[o];
#pragma unroll 8
  for (int k = 0; k < 192; k++) acc += hS[qq][k] * w2S[o][k];
  const int q = q0 + qq;
  const int b = q / 1000, node = q - b * 1000;
  out[(size_t)b * 12000 + o * 1000 + node] = acc;
}

// ============================================================
extern "C" void kernel_launch(void* const* d_in, const int* in_sizes, int n_in,
                              void* d_out, int out_size, void* d_ws, size_t ws_size,
                              hipStream_t stream)
{
  const float* x     = (const float*)d_in[0];
  const float* A     = (const float*)d_in[1];
  const float* FSP   = (const float*)d_in[2];
  const float* DSP   = (const float*)d_in[3];
  const float* E1    = (const float*)d_in[4];
  const float* E2    = (const float*)d_in[5];
  const float* fus_W = (const float*)d_in[6];
  const float* fus_b = (const float*)d_in[7];
  const float* fus_v = (const float*)d_in[8];
  const float* beta1 = (const float*)d_in[9];
  const float* beta2 = (const float*)d_in[10];
  const float* gcn_W1= (const float*)d_in[11];
  const float* gcn_b1= (const float*)d_in[12];
  const float* ln1g  = (const float*)d_in[13];
  const float* ln1b  = (const float*)d_in[14];
  const float* gcn_W2= (const float*)d_in[15];
  const float* gcn_b2= (const float*)d_in[16];
  const float* ln2g  = (const float*)d_in[17];
  const float* ln2b  = (const float*)d_in[18];
  const float* Wih0  = (const float*)d_in[19];
  const float* Whh0  = (const float*)d_in[20];
  const float* bih0  = (const float*)d_in[21];
  const float* bhh0  = (const float*)d_in[22];
  const float* Wih1  = (const float*)d_in[23];
  const float* Whh1  = (const float*)d_in[24];
  const float* bih1  = (const float*)d_in[25];
  const float* bhh1  = (const float*)d_in[26];
  const float* att_w = (const float*)d_in[27];
  const float* fc1W  = (const float*)d_in[28];
  const float* fc1b  = (const float*)d_in[29];
  const float* fc2W  = (const float*)d_in[30];
  const float* fc2b  = (const float*)d_in[31];
  float* out = (float*)d_out;

  char* w = (char*)d_ws;
  auto alloc = [&](size_t bytes) -> char* {
    char* p = w;
    w += (bytes + 255) & ~(size_t)255;
    return p;
  };

  float* consts  = (float*)alloc(8 * 4);
  float* scp     = (float*)alloc(3 * 4);
  float* alphap  = (float*)alloc(3 * 4);
  float* rowsums = (float*)alloc(3000 * 4);
  float* dinvp   = (float*)alloc(1000 * 4);
  u16*   Gbuf    = (u16*)alloc((size_t)3000000 * 2);
  u16*   Sbf     = (u16*)alloc((size_t)1024 * 1024 * 2);
  u16*   xbf     = (u16*)alloc((size_t)384000 * 2);
  u16*   fusWbf  = (u16*)alloc((size_t)32000 * 2);
  u16*   Wih0b   = (u16*)alloc((size_t)55296 * 2);
  u16*   Whh0b   = (u16*)alloc((size_t)110592 * 2);
  u16*   Wih1b   = (u16*)alloc((size_t)110592 * 2);
  u16*   Whh1b   = (u16*)alloc((size_t)110592 * 2);
  u16*   w1s     = (u16*)alloc((size_t)192 * 576 * 2);
  u16*   W2s     = (u16*)alloc((size_t)96 * 192 * 2);
  float4* cwpk   = (float4*)alloc((size_t)96 * 16);
  float* Pbuf    = (float*)alloc((size_t)96000 * 4);
  float* yt      = (float*)alloc((size_t)384000 * 4);
  u16*   h2t     = (u16*)alloc((size_t)36864 * 1024 * 2);  // 75.5 MB; states/FC alias later
  u16*   Gg      = (u16*)alloc((size_t)36864000 * 2);      // 73.7 MB
  float* Nv      = (float*)alloc((size_t)6144000 * 4);
  float* Mbuf    = (float*)alloc((size_t)32000 * 4);
  float* Lbuf    = (float*)alloc((size_t)32000 * 4);
  float* score   = (float*)alloc((size_t)32000 * 4);

  // GRU state double-buffers alias the h2t region (dead after k_bigemm)
  u16* h0buf[2] = { h2t,                    h2t + (size_t)6144000 };
  u16* h1buf[2] = { h2t + (size_t)12288000, h2t + (size_t)18432000 };
  // FC-head aliases (states dead after GRU loop)
  u16*   ctxs = h2t;
  float* hfc  = (float*)(h2t + (size_t)18432000);

  k_prep<<<3174, 256, 0, stream>>>(x, fus_W, Wih0, Whh0, Wih1, Whh1, gcn_W1, gcn_b1,
                                   gcn_W2, ln1g, ln1b,
                                   xbf, fusWbf, Wih0b, Whh0b, Wih1b, Whh1b, W2s, cwpk, consts);
  k_w1split<<<144, 256, 0, stream>>>(fc1W, w1s);
  k_zero<<<557, 256, 0, stream>>>(h2t, score);
  k_adjrow<<<1000, 256, 0, stream>>>(A, FSP, DSP, E1, E2, beta1, beta2, Gbuf, rowsums);
  gemm_nt<0><<<dim3(1, 24), 256, 0, stream>>>(Gbuf, 1000, fusWbf, 1000, Pbuf, 32, 3000, 32, 1000, nullptr);
  k_sc<<<3, 256, 0, stream>>>(Pbuf, fus_b, fus_v, scp);
  k_alpha<<<1, 256, 0, stream>>>(scp, rowsums, alphap, dinvp);
  k_shat<<<4000, 256, 0, stream>>>(Gbuf, alphap, dinvp, Sbf);
  // yt[m, r] = sum_n S[m,n] * x[r,n]
  gemm_nt<0><<<dim3(6, 8), 256, 0, stream>>>(Sbf, 1024, xbf, 1000, yt, 384, 1000, 384, 1000, nullptr);
  // h2t = Hln @ W2 (LN1 fused, LDS-transposed coalesced stores)
  k_h2gemm<<<3000, 256, 0, stream>>>(yt, cwpk, W2s, consts, h2t);
  // Gg = S @ h2t^T  (73.7 GFLOP)
  k_bigemm<<<2304, 256, 0, stream>>>(Sbf, h2t, Gg);
  k_ln2g<<<1500, 256, 0, stream>>>(Gg, gcn_b2, ln2g, ln2b);

  for (int t = 0; t < 12; ++t) {
    u16* h0in  = h0buf[t & 1];
    u16* h0out = h0buf[(t & 1) ^ 1];
    u16* h1in  = h1buf[t & 1];
    u16* h1out = h1buf[(t & 1) ^ 1];
    k_gru<96, false><<<dim3(6, 250), 256, 0, stream>>>(
        Gg + t * 96, 1152, Wih0b, h0in, Whh0b, bih0, bhh0, h0out, nullptr, nullptr, t == 0);
    k_gru<192, true><<<dim3(6, 250), 256, 0, stream>>>(
        h0out, 192, Wih1b, h1in, Whh1b, bih1, bhh1, h1out, att_w, score, t == 0);
    k_pool<<<4000, 256, 0, stream>>>(h1out, score, Mbuf, Lbuf, Nv, t == 0);
  }

  // FC head
  k_ctxsplit<<<24000, 256, 0, stream>>>(Nv, Lbuf, ctxs);
  gemm_nt<3><<<dim3(3, 250), 256, 0, stream>>>(ctxs, 576, w1s, 576, hfc, 192, 32000, 192, 576, fc1b);
  k_fc2<<<2000, 192, 0, stream>>>(hfc, fc2W, fc2b, out);
}

// Round 9
// 1512.326 us; speedup vs baseline: 2.6114x; 1.0919x over previous
//
#include <hip/hip_runtime.h>

typedef unsigned short u16;
typedef unsigned int u32;
typedef __attribute__((ext_vector_type(8))) short short8;   // 8 x bf16 (4 VGPRs)
typedef __attribute__((ext_vector_type(4))) float float4v;  // 4 x f32

#define DEV static __device__ __forceinline__

DEV float bf2f(u16 u) { u32 x = ((u32)u) << 16; float f; __builtin_memcpy(&f, &x, 4); return f; }
DEV u16 f2bf(float f) {
  u32 u; __builtin_memcpy(&u, &f, 4);
  u = (u + 0x7fffu + ((u >> 16) & 1u)) >> 16;
  return (u16)u;
}
DEV float sigm(float x) { return 1.f / (1.f + __expf(-x)); }

// async global->LDS, 16B per lane; LDS dest = wave-uniform base + lane*16
DEV void gl16(const u16* g, u16* l) {
  __builtin_amdgcn_global_load_lds(
      (const __attribute__((address_space(1))) void*)g,
      (__attribute__((address_space(3))) void*)l, 16, 0, 0);
}

// ============================================================
// Generic GEMM (small cases): C[M,N] = A[M,K](bf16) * B[N,K](bf16 "NK")
// OMODE: 0 = f32 row-major, 3 = f32 + bias + tanh-GELU epilogue (fc1)
// ============================================================
template <int OMODE>
__launch_bounds__(256)
__global__ void gemm_nt(const u16* __restrict__ A, int lda,
                        const u16* __restrict__ B, int ldb,
                        void* __restrict__ Cp, int ldc,
                        int M, int N, int K,
                        const float* __restrict__ bias)
{
  constexpr int PK = 40;
  __shared__ u16 As[128 * PK];
  __shared__ u16 Bs[64 * PK];

  const int tid  = threadIdx.x;
  const int m0   = blockIdx.y * 128;
  const int n0   = blockIdx.x * 64;
  const int wid  = tid >> 6;
  const int lane = tid & 63;
  const int l15  = lane & 15;
  const int quad = lane >> 4;
  const int wm   = (wid >> 1) * 64;
  const int wn   = (wid & 1) * 32;

  float4v acc[4][2];
  const float4v fz = {0.f, 0.f, 0.f, 0.f};
#pragma unroll
  for (int i = 0; i < 4; i++)
#pragma unroll
    for (int j = 0; j < 2; j++) acc[i][j] = fz;

  const int arow = tid >> 2;
  const int akc  = tid & 3;

  const int kt_count = (K + 31) / 32;
  for (int kt = 0; kt < kt_count; ++kt) {
    const int k0 = kt * 32 + akc * 8;
    const bool kok = (k0 < K);
    uint4 av0 = make_uint4(0, 0, 0, 0), av1 = av0, bv = av0;
    int ra = m0 + arow;
    if (kok && ra < M)        av0 = *(const uint4*)(A + (size_t)ra * lda + k0);
    if (kok && ra + 64 < M)   av1 = *(const uint4*)(A + (size_t)(ra + 64) * lda + k0);
    int rb = n0 + arow;
    if (kok && rb < N)        bv  = *(const uint4*)(B + (size_t)rb * ldb + k0);

    __syncthreads();
    *(uint4*)&As[arow * PK + akc * 8]        = av0;
    *(uint4*)&As[(arow + 64) * PK + akc * 8] = av1;
    *(uint4*)&Bs[arow * PK + akc * 8]        = bv;
    __syncthreads();

    short8 af[4], bfr[2];
#pragma unroll
    for (int i = 0; i < 4; i++)
      af[i] = *(const short8*)&As[(wm + i * 16 + l15) * PK + quad * 8];
#pragma unroll
    for (int j = 0; j < 2; j++)
      bfr[j] = *(const short8*)&Bs[(wn + j * 16 + l15) * PK + quad * 8];
#pragma unroll
    for (int i = 0; i < 4; i++)
#pragma unroll
      for (int j = 0; j < 2; j++)
        acc[i][j] = __builtin_amdgcn_mfma_f32_16x16x32_bf16(af[i], bfr[j], acc[i][j], 0, 0, 0);
  }

#pragma unroll
  for (int i = 0; i < 4; i++)
#pragma unroll
    for (int j = 0; j < 2; j++)
#pragma unroll
      for (int e = 0; e < 4; e++) {
        int r = m0 + wm + i * 16 + quad * 4 + e;
        int c = n0 + wn + j * 16 + l15;
        if (r < M && c < N) {
          float v = acc[i][j][e];
          if (OMODE == 0) ((float*)Cp)[(size_t)r * ldc + c] = v;
          else {
            float a = v + bias[c];
            float t = tanhf(0.7978845608028654f * (a + 0.044715f * a * a * a));
            ((float*)Cp)[(size_t)r * ldc + c] = 0.5f * a * (1.f + t);
          }
        }
      }
}

// ============================================================
// Big graph-conv GEMM: Gg = S(1000x1024) @ h2t(36864x1024)^T
// 128x128x32, global_load_lds(16B), XOR-swizzled LDS (kills 8-way
// ds_read conflicts), XCD swizzle, g-layout scatter.
// ============================================================
__launch_bounds__(256)
__global__ void k_bigemm(const u16* __restrict__ A,
                         const u16* __restrict__ B,
                         u16* __restrict__ Gg)
{
  __shared__ u16 As[128 * 32];
  __shared__ u16 Bs[128 * 32];
  const int tid  = threadIdx.x;
  const int bid  = blockIdx.x;
  const int xcd  = bid & 7;
  const int jj   = bid >> 3;
  const int m0   = (jj & 7) * 128;
  const int n0   = (xcd + 8 * (jj >> 3)) * 128;

  const int wid  = tid >> 6;
  const int lane = tid & 63;
  const int l15  = lane & 15;
  const int quad = lane >> 4;
  const int wm   = (wid >> 1) * 64;
  const int wn   = (wid & 1) * 64;

  const int srow = wid * 16 + (lane >> 2);
  const int skc  = (((lane & 3) ^ ((lane >> 2) & 3))) * 8;   // swizzled source chunk

  const u16* agp0 = A + (size_t)(m0 + srow) * 1024 + skc;
  const u16* agp1 = agp0 + (size_t)64 * 1024;
  const u16* bgp0 = B + (size_t)(n0 + srow) * 1024 + skc;
  const u16* bgp1 = bgp0 + (size_t)64 * 1024;
  u16* asl0 = &As[(wid * 16) * 32];
  u16* asl1 = &As[(64 + wid * 16) * 32];
  u16* bsl0 = &Bs[(wid * 16) * 32];
  u16* bsl1 = &Bs[(64 + wid * 16) * 32];

  float4v acc[4][4];
  const float4v fz = {0.f, 0.f, 0.f, 0.f};
#pragma unroll
  for (int i = 0; i < 4; i++)
#pragma unroll
    for (int j = 0; j < 4; j++) acc[i][j] = fz;

  const int swa = (quad ^ (l15 & 3)) * 8;   // swizzled read offset

  for (int kt = 0; kt < 32; ++kt) {
    const int ko = kt * 32;
    gl16(agp0 + ko, asl0);
    gl16(agp1 + ko, asl1);
    gl16(bgp0 + ko, bsl0);
    gl16(bgp1 + ko, bsl1);
    __syncthreads();
    short8 af[4], bf[4];
#pragma unroll
    for (int i = 0; i < 4; i++)
      af[i] = *(const short8*)&As[(wm + i * 16 + l15) * 32 + swa];
#pragma unroll
    for (int j = 0; j < 4; j++)
      bf[j] = *(const short8*)&Bs[(wn + j * 16 + l15) * 32 + swa];
#pragma unroll
    for (int i = 0; i < 4; i++)
#pragma unroll
      for (int j = 0; j < 4; j++)
        acc[i][j] = __builtin_amdgcn_mfma_f32_16x16x32_bf16(af[i], bf[j], acc[i][j], 0, 0, 0);
    __syncthreads();
  }

#pragma unroll
  for (int i = 0; i < 4; i++)
#pragma unroll
    for (int j = 0; j < 4; j++)
#pragma unroll
      for (int e = 0; e < 4; e++) {
        int r = m0 + wm + i * 16 + quad * 4 + e;
        if (r < 1000) {
          int c = n0 + wn + j * 16 + l15;
          int rs = c / 96, cc = c - rs * 96;
          Gg[(size_t)rs * 96000 + (size_t)r * 96 + cc] = f2bf(acc[i][j][e]);
        }
      }
}

// ============================================================
// Fused GRU step, 6-way N split: BM=128, 32 cols per gate per block.
// K=192 phases use BK=64 (half the barrier drains); K=96 X-phase BK=32.
// XOR-swizzled LDS staging -> ~2-way (free) ds_read conflicts.
// POOL: partial attention scores via butterfly + atomicAdd.
// ============================================================
template <int KX, bool POOL>
__launch_bounds__(256)
__global__ void k_gru(const u16* __restrict__ Xin, int ldx,
                      const u16* __restrict__ Win,
                      const u16* __restrict__ Hin,
                      const u16* __restrict__ Whh,
                      const float* __restrict__ bih, const float* __restrict__ bhh,
                      u16* __restrict__ Hout,
                      const float* __restrict__ att_w, float* __restrict__ score,
                      int t0)
{
  __shared__ u16 As[128 * 64];   // 16 KB (BK=64); BK=32 path uses pitch-32 region
  __shared__ u16 Bs[96 * 64];    // 12 KB
  const int tid  = threadIdx.x;
  const int m0   = blockIdx.y * 128;
  const int c0   = blockIdx.x * 32;      // 32 cols per gate
  const int wid  = tid >> 6;
  const int lane = tid & 63;
  const int l15  = lane & 15;
  const int quad = lane >> 4;
  const int wm   = wid * 32;             // 4 waves x 32 rows

  const int srow8 = lane >> 3;                      // BK=64 staging row-in-wave
  const int sw8   = ((lane & 7) ^ srow8) * 8;       // swizzled source chunk
  const int srow4 = lane >> 2;                      // BK=32 staging
  const int sw4   = (((lane & 3) ^ (srow4 & 3))) * 8;

  float4v aR[2][2], aZ[2][2], aXN[2][2], aHN[2][2];
  const float4v fz = {0.f, 0.f, 0.f, 0.f};
#pragma unroll
  for (int i = 0; i < 2; i++)
#pragma unroll
    for (int j = 0; j < 2; j++) { aR[i][j] = fz; aZ[i][j] = fz; aXN[i][j] = fz; aHN[i][j] = fz; }

  // ---- phase X ----
  if (KX == 96) {
    // BK=32 x 3 (K=96)
    const u16* ax0 = Xin + (size_t)(m0 + wid * 16 + srow4) * ldx + sw4;
    const u16* ax1 = Xin + (size_t)(m0 + 64 + wid * 16 + srow4) * ldx + sw4;
    const int b0 = wid * 16 + srow4;                // Bs rows 0..63
    const u16* bx0 = Win + (size_t)((b0 >> 5) * 192 + c0 + (b0 & 31)) * 96 + sw4;
    const int b1 = 64 + wid * 16 + srow4;           // Bs rows 64..95 (wid<2)
    const u16* bx1 = Win + (size_t)(384 + c0 + (b1 & 31)) * 96 + sw4;
    u16* asl0 = &As[(wid * 16) * 32];
    u16* asl1 = &As[(64 + wid * 16) * 32];
    u16* bsl0 = &Bs[(wid * 16) * 32];
    u16* bsl1 = &Bs[(64 + wid * 16) * 32];
    const int swa = (quad ^ (l15 & 3)) * 8;
#pragma unroll
    for (int kt = 0; kt < 3; ++kt) {
      const int ko = kt * 32;
      gl16(ax0 + ko, asl0); gl16(ax1 + ko, asl1);
      gl16(bx0 + ko, bsl0);
      if (wid < 2) gl16(bx1 + ko, bsl1);
      __syncthreads();
      short8 af[2], bR[2], bZ[2], bN[2];
#pragma unroll
      for (int i = 0; i < 2; i++)
        af[i] = *(const short8*)&As[(wm + i * 16 + l15) * 32 + swa];
#pragma unroll
      for (int j = 0; j < 2; j++) {
        bR[j] = *(const short8*)&Bs[(j * 16 + l15) * 32 + swa];
        bZ[j] = *(const short8*)&Bs[(32 + j * 16 + l15) * 32 + swa];
        bN[j] = *(const short8*)&Bs[(64 + j * 16 + l15) * 32 + swa];
      }
#pragma unroll
      for (int i = 0; i < 2; i++)
#pragma unroll
        for (int j = 0; j < 2; j++) {
          aR[i][j]  = __builtin_amdgcn_mfma_f32_16x16x32_bf16(af[i], bR[j], aR[i][j], 0, 0, 0);
          aZ[i][j]  = __builtin_amdgcn_mfma_f32_16x16x32_bf16(af[i], bZ[j], aZ[i][j], 0, 0, 0);
          aXN[i][j] = __builtin_amdgcn_mfma_f32_16x16x32_bf16(af[i], bN[j], aXN[i][j], 0, 0, 0);
        }
      __syncthreads();
    }
  } else {
    // KX=192: BK=64 x 3
    const u16* abase = Xin + (size_t)(m0 + wid * 8 + srow8) * 192 + sw8;
    const u16* bbase = Win + (size_t)(c0 + wid * 8 + srow8) * 192 + sw8;
#pragma unroll
    for (int kt = 0; kt < 3; ++kt) {
      const int ko = kt * 64;
#pragma unroll
      for (int c = 0; c < 4; c++)
        gl16(abase + (size_t)c * 32 * 192 + ko, &As[(c * 32 + wid * 8) * 64]);
#pragma unroll
      for (int c = 0; c < 3; c++)
        gl16(bbase + (size_t)c * 192 * 192 + ko, &Bs[(c * 32 + wid * 8) * 64]);
      __syncthreads();
#pragma unroll
      for (int k32 = 0; k32 < 2; k32++) {
        const int swr = ((quad + 4 * k32) ^ (l15 & 7)) * 8;
        short8 af[2], bR[2], bZ[2], bN[2];
#pragma unroll
        for (int i = 0; i < 2; i++)
          af[i] = *(const short8*)&As[(wm + i * 16 + l15) * 64 + swr];
#pragma unroll
        for (int j = 0; j < 2; j++) {
          bR[j] = *(const short8*)&Bs[(j * 16 + l15) * 64 + swr];
          bZ[j] = *(const short8*)&Bs[(32 + j * 16 + l15) * 64 + swr];
          bN[j] = *(const short8*)&Bs[(64 + j * 16 + l15) * 64 + swr];
        }
#pragma unroll
        for (int i = 0; i < 2; i++)
#pragma unroll
          for (int j = 0; j < 2; j++) {
            aR[i][j]  = __builtin_amdgcn_mfma_f32_16x16x32_bf16(af[i], bR[j], aR[i][j], 0, 0, 0);
            aZ[i][j]  = __builtin_amdgcn_mfma_f32_16x16x32_bf16(af[i], bZ[j], aZ[i][j], 0, 0, 0);
            aXN[i][j] = __builtin_amdgcn_mfma_f32_16x16x32_bf16(af[i], bN[j], aXN[i][j], 0, 0, 0);
          }
      }
      __syncthreads();
    }
  }
  // ---- phase H: K=192, BK=64 x 3 ----
  if (!t0) {
    const u16* abase = Hin + (size_t)(m0 + wid * 8 + srow8) * 192 + sw8;
    const u16* bbase = Whh + (size_t)(c0 + wid * 8 + srow8) * 192 + sw8;
#pragma unroll
    for (int kt = 0; kt < 3; ++kt) {
      const int ko = kt * 64;
#pragma unroll
      for (int c = 0; c < 4; c++)
        gl16(abase + (size_t)c * 32 * 192 + ko, &As[(c * 32 + wid * 8) * 64]);
#pragma unroll
      for (int c = 0; c < 3; c++)
        gl16(bbase + (size_t)c * 192 * 192 + ko, &Bs[(c * 32 + wid * 8) * 64]);
      __syncthreads();
#pragma unroll
      for (int k32 = 0; k32 < 2; k32++) {
        const int swr = ((quad + 4 * k32) ^ (l15 & 7)) * 8;
        short8 af[2], bR[2], bZ[2], bN[2];
#pragma unroll
        for (int i = 0; i < 2; i++)
          af[i] = *(const short8*)&As[(wm + i * 16 + l15) * 64 + swr];
#pragma unroll
        for (int j = 0; j < 2; j++) {
          bR[j] = *(const short8*)&Bs[(j * 16 + l15) * 64 + swr];
          bZ[j] = *(const short8*)&Bs[(32 + j * 16 + l15) * 64 + swr];
          bN[j] = *(const short8*)&Bs[(64 + j * 16 + l15) * 64 + swr];
        }
#pragma unroll
        for (int i = 0; i < 2; i++)
#pragma unroll
          for (int j = 0; j < 2; j++) {
            aR[i][j]  = __builtin_amdgcn_mfma_f32_16x16x32_bf16(af[i], bR[j], aR[i][j], 0, 0, 0);
            aZ[i][j]  = __builtin_amdgcn_mfma_f32_16x16x32_bf16(af[i], bZ[j], aZ[i][j], 0, 0, 0);
            aHN[i][j] = __builtin_amdgcn_mfma_f32_16x16x32_bf16(af[i], bN[j], aHN[i][j], 0, 0, 0);
          }
      }
      __syncthreads();
    }
  }

  // ---- epilogue: gates + state write (+ pooling partials) ----
  float ps[2][4];
  if (POOL) {
#pragma unroll
    for (int i = 0; i < 2; i++)
#pragma unroll
      for (int e = 0; e < 4; e++) ps[i][e] = 0.f;
  }
#pragma unroll
  for (int j = 0; j < 2; ++j) {
    const int c = c0 + j * 16 + l15;
    const float brz = bih[c] + bhh[c];
    const float bzz = bih[192 + c] + bhh[192 + c];
    const float bxn = bih[384 + c];
    const float bhn = bhh[384 + c];
    const float aw  = POOL ? att_w[c] : 0.f;
#pragma unroll
    for (int i = 0; i < 2; ++i)
#pragma unroll
      for (int e = 0; e < 4; ++e) {
        const int row = m0 + wm + i * 16 + quad * 4 + e;
        float rg  = sigm(aR[i][j][e] + brz);
        float zg  = sigm(aZ[i][j][e] + bzz);
        float hnv = bhn + (t0 ? 0.f : aHN[i][j][e]);
        float ng  = tanhf(aXN[i][j][e] + bxn + rg * hnv);
        float hold = t0 ? 0.f : bf2f(Hin[(size_t)row * 192 + c]);
        float hnew = (1.f - zg) * ng + zg * hold;
        Hout[(size_t)row * 192 + c] = f2bf(hnew);
        if (POOL) ps[i][e] += hnew * aw;
      }
  }
  if (POOL) {
#pragma unroll
    for (int i = 0; i < 2; ++i)
#pragma unroll
      for (int e = 0; e < 4; ++e) {
        float v = ps[i][e];
        v += __shfl_xor(v, 1); v += __shfl_xor(v, 2);
        v += __shfl_xor(v, 4); v += __shfl_xor(v, 8);
        if (l15 == 0) atomicAdd(&score[m0 + wm + i * 16 + quad * 4 + e], v);
      }
  }
}

// online-softmax pooling: 8 q per 256-thread block, per-thread recompute of
// (Mn, so, wn) -- no broadcast chain. tid<8 owns the M/L/score writes.
__launch_bounds__(256)
__global__ void k_pool(const u16* __restrict__ H, float* __restrict__ score,
                       float* __restrict__ Mbuf, float* __restrict__ Lbuf,
                       float* __restrict__ Nv, int t0)
{
  const int base = blockIdx.x * 1536;   // 8 q * 192
  const int tid  = threadIdx.x;

  float prev[6], hnew[6], so[6], wn[6];
#pragma unroll
  for (int k = 0; k < 6; k++) {
    const int idx = base + tid + k * 256;
    const int q = idx / 192;
    const float s = score[q];
    hnew[k] = bf2f(H[idx]);
    if (t0) {
      so[k] = 0.f; wn[k] = 1.f; prev[k] = 0.f;
    } else {
      const float Mo = Mbuf[q];
      const float Mn = fmaxf(Mo, s);
      so[k] = __expf(Mo - Mn);
      wn[k] = __expf(s - Mn);
      prev[k] = Nv[idx];
    }
  }
  float Mw = 0.f, Lw = 0.f;
  int qw = -1;
  if (tid < 8) {
    qw = blockIdx.x * 8 + tid;
    const float s = score[qw];
    if (t0) { Mw = s; Lw = 1.f; }
    else {
      const float Mo = Mbuf[qw];
      const float Mn = fmaxf(Mo, s);
      Mw = Mn;
      Lw = Lbuf[qw] * __expf(Mo - Mn) + __expf(s - Mn);
    }
  }
  __syncthreads();
  if (tid < 8) { Mbuf[qw] = Mw; Lbuf[qw] = Lw; score[qw] = 0.f; }
#pragma unroll
  for (int k = 0; k < 6; k++) {
    const int idx = base + tid + k * 256;
    Nv[idx] = prev[k] * so[k] + wn[k] * hnew[k];
  }
}

// ============================================================
// H2 GEMM: h2t[(r*96+c2)*1024+n] = Hln @ W2 (analytic LN1 in A-staging)
// Epilogue: LDS-transpose + coalesced dwordx4 stores along n.
// ============================================================
__launch_bounds__(256)
__global__ void k_h2gemm(const float* __restrict__ yt, const float4* __restrict__ cwpk,
                         const u16* __restrict__ W2s, const float* __restrict__ consts,
                         u16* __restrict__ h2t)
{
  constexpr int PK = 40;
  __shared__ u16 As[128 * PK];
  __shared__ u16 Bs[96 * PK];
  __shared__ u16 Ts[96 * 136];   // transpose staging, pitch 136 (16B-aligned rows)

  const int tid  = threadIdx.x;
  const int m0   = blockIdx.x * 128;
  const int wid  = tid >> 6;
  const int lane = tid & 63;
  const int l15  = lane & 15;
  const int quad = lane >> 4;
  const int wm   = (wid >> 1) * 64;
  const int wn   = (wid & 1) * 48;

  const float P = consts[0], Q = consts[1], VW = consts[2], CWB = consts[3], VB = consts[4];

  const int arow = tid >> 2;
  const int akc  = tid & 3;

  float yv[2], mu[2], iv[2];
#pragma unroll
  for (int rr = 0; rr < 2; rr++) {
    int i = m0 + arow + rr * 64;
    int r = i / 1000, n = i - r * 1000;
    float y = yt[n * 384 + r];
    yv[rr] = y;
    mu[rr] = y * P + Q;
    iv[rr] = rsqrtf(y * y * VW + 2.f * y * CWB + VB + 1e-5f);
  }

  float4v acc[4][3];
  const float4v fz = {0.f, 0.f, 0.f, 0.f};
#pragma unroll
  for (int i = 0; i < 4; i++)
#pragma unroll
    for (int j = 0; j < 3; j++) acc[i][j] = fz;

  uint4 asave[2][3];
  const bool has2 = (arow < 32);

  for (int kt = 0; kt < 6; ++kt) {
    const int k0 = kt * 32 + akc * 8;
    uint4 av[2];
    if (kt < 3) {
#pragma unroll
      for (int rr = 0; rr < 2; rr++) {
        u16 hb[8];
#pragma unroll
        for (int e = 0; e < 8; e++) {
          float4 cw = cwpk[k0 + e];
          float t = yv[rr] * cw.x + cw.y - mu[rr];
          float h = fmaxf(t * iv[rr] * cw.z + cw.w, 0.f);
          hb[e] = f2bf(h);
        }
        __builtin_memcpy(&av[rr], hb, 16);
        asave[rr][kt] = av[rr];
      }
    } else {
      av[0] = asave[0][kt - 3];
      av[1] = asave[1][kt - 3];
    }
    uint4 bv0 = *(const uint4*)(W2s + (size_t)arow * 192 + k0);
    uint4 bv1 = make_uint4(0, 0, 0, 0);
    if (has2) bv1 = *(const uint4*)(W2s + (size_t)(arow + 64) * 192 + k0);

    __syncthreads();
    *(uint4*)&As[arow * PK + akc * 8]        = av[0];
    *(uint4*)&As[(arow + 64) * PK + akc * 8] = av[1];
    *(uint4*)&Bs[arow * PK + akc * 8]        = bv0;
    if (has2) *(uint4*)&Bs[(arow + 64) * PK + akc * 8] = bv1;
    __syncthreads();

    short8 af[4], bfr[3];
#pragma unroll
    for (int i = 0; i < 4; i++)
      af[i] = *(const short8*)&As[(wm + i * 16 + l15) * PK + quad * 8];
#pragma unroll
    for (int j = 0; j < 3; j++)
      bfr[j] = *(const short8*)&Bs[(wn + j * 16 + l15) * PK + quad * 8];
#pragma unroll
    for (int i = 0; i < 4; i++)
#pragma unroll
      for (int j = 0; j < 3; j++)
        acc[i][j] = __builtin_amdgcn_mfma_f32_16x16x32_bf16(af[i], bfr[j], acc[i][j], 0, 0, 0);
  }

  // transpose tile into LDS: Ts[c2][row_local]
#pragma unroll
  for (int i = 0; i < 4; i++)
#pragma unroll
    for (int j = 0; j < 3; j++)
#pragma unroll
      for (int e = 0; e < 4; e++) {
        int rowl = wm + i * 16 + quad * 4 + e;
        int c2   = wn + j * 16 + l15;
        Ts[c2 * 136 + rowl] = f2bf(acc[i][j][e]);
      }
  __syncthreads();
  // coalesced stores: 8-wide n-chunks never cross the r-boundary (1000 % 8 == 0)
#pragma unroll
  for (int u = tid; u < 1536; u += 256) {
    int c2 = u >> 4, ch = u & 15;
    int iidx0 = m0 + ch * 8;
    int r = iidx0 / 1000, n0 = iidx0 - r * 1000;
    *(uint4*)(h2t + (size_t)(r * 96 + c2) * 1024 + n0) = *(const uint4*)&Ts[c2 * 136 + ch * 8];
  }
}

// ============================================================
// prep: f32 -> bf16 conversions + W1/b1 moment stats + W2 split + cw pack
// ============================================================
__launch_bounds__(256)
__global__ void k_prep(const float* x, const float* fus_W,
                       const float* Wih0, const float* Whh0,
                       const float* Wih1, const float* Whh1,
                       const float* gcn_W1, const float* gcn_b1,
                       const float* gcn_W2, const float* ln1g, const float* ln1b,
                       u16* xbf, u16* fusWbf, u16* Wih0b, u16* Whh0b, u16* Wih1b, u16* Whh1b,
                       u16* W2s, float4* cwpk, float* consts)
{
  long o = (long)blockIdx.x * 256 + threadIdx.x;
  if (o < 384000) xbf[o] = f2bf(x[o]);
  else if ((o -= 384000) < 32000) fusWbf[o] = f2bf(fus_W[o]);
  else if ((o -= 32000) < 55296)  Wih0b[o] = f2bf(Wih0[o]);
  else if ((o -= 55296) < 110592) Whh0b[o] = f2bf(Whh0[o]);
  else if ((o -= 110592) < 110592) Wih1b[o] = f2bf(Wih1[o]);
  else if ((o -= 110592) < 110592) Whh1b[o] = f2bf(Whh1[o]);
  else if ((o -= 110592) < 9216) {
    int c2 = (int)o / 96, c = (int)o - c2 * 96;
    float wv = gcn_W2[c * 96 + c2];
    u16 hi = f2bf(wv);
    u16 lo = f2bf(wv - bf2f(hi));
    W2s[c2 * 192 + c] = hi;
    W2s[c2 * 192 + 96 + c] = lo;
  }
  else if ((o -= 9216) < 96) {
    int c = (int)o;
    float4 cw;
    cw.x = gcn_W1[c]; cw.y = gcn_b1[c]; cw.z = ln1g[c]; cw.w = ln1b[c];
    cwpk[c] = cw;
  }
  if (blockIdx.x == 0 && threadIdx.x == 0) {
    float sw = 0, sb = 0, sww = 0, swb = 0, sbb = 0;
    for (int c = 0; c < 96; c++) {
      float wv = gcn_W1[c], b = gcn_b1[c];
      sw += wv; sb += b; sww += wv * wv; swb += wv * b; sbb += b * b;
    }
    float P = sw / 96.f, Q = sb / 96.f;
    consts[0] = P; consts[1] = Q;
    consts[2] = sww / 96.f - P * P;
    consts[3] = swb / 96.f - P * Q;
    consts[4] = sbb / 96.f - Q * Q;
  }
}

// zero-fill: h2t K-pad columns (1000..1023) + score buffer
__launch_bounds__(256)
__global__ void k_zero(u16* __restrict__ h2t, float* __restrict__ score)
{
  int idx = blockIdx.x * 256 + threadIdx.x;
  if (idx < 110592) {
    int row = idx / 3, p = idx - row * 3;
    *(uint4*)(h2t + (size_t)row * 1024 + 1000 + p * 8) = make_uint4(0, 0, 0, 0);
  } else if ((idx -= 110592) < 32000) {
    score[idx] = 0.f;
  }
}

// fc1W (192x192 f32) -> split-bf16 B' (192 x 576): [wh | wl | wh]
__launch_bounds__(256)
__global__ void k_w1split(const float* __restrict__ fc1W, u16* __restrict__ w1s)
{
  int idx = blockIdx.x * 256 + threadIdx.x;
  if (idx >= 192 * 192) return;
  int n = idx / 192, k = idx - n * 192;
  float w = fc1W[idx];
  u16 hi = f2bf(w);
  u16 lo = f2bf(w - bf2f(hi));
  w1s[(size_t)n * 576 + k]       = hi;
  w1s[(size_t)n * 576 + 192 + k] = lo;
  w1s[(size_t)n * 576 + 384 + k] = hi;
}

// ============================================================
// per-row: Aadp softmax row + the 3 candidate graphs (bf16) + row sums
// ============================================================
__launch_bounds__(256)
__global__ void k_adjrow(const float* __restrict__ A, const float* __restrict__ FSP,
                         const float* __restrict__ DSP, const float* __restrict__ E1,
                         const float* __restrict__ E2,
                         const float* beta1, const float* beta2,
                         u16* __restrict__ G, float* __restrict__ rowsums)
{
  __shared__ float z[1000];
  __shared__ float red[256];
  const int n = blockIdx.x, tid = threadIdx.x;

  float e1r[10];
#pragma unroll
  for (int d = 0; d < 10; d++) e1r[d] = E1[n * 10 + d];

  float lmax = -1e30f;
  for (int m = tid; m < 1000; m += 256) {
    float s = 0;
#pragma unroll
    for (int d = 0; d < 10; d++) s += e1r[d] * E2[m * 10 + d];
    s = fmaxf(s, 0.f);
    z[m] = s;
    lmax = fmaxf(lmax, s);
  }
  red[tid] = lmax; __syncthreads();
  for (int st = 128; st > 0; st >>= 1) { if (tid < st) red[tid] = fmaxf(red[tid], red[tid + st]); __syncthreads(); }
  const float mx = red[0]; __syncthreads();

  float lsum = 0;
  for (int m = tid; m < 1000; m += 256) { float e = __expf(z[m] - mx); z[m] = e; lsum += e; }
  red[tid] = lsum; __syncthreads();
  for (int st = 128; st > 0; st >>= 1) { if (tid < st) red[tid] += red[tid + st]; __syncthreads(); }
  const float inv = 1.f / red[0]; __syncthreads();

  const float w1 = sigm(beta1[0]);
  const float w2 = sigm(beta2[0]);
  float s0 = 0, s1 = 0, s2 = 0;
  for (int m = tid; m < 1000; m += 256) {
    float aadp = z[m] * inv;
    float a = A[n * 1000 + m], f = FSP[n * 1000 + m], dd = DSP[n * 1000 + m];
    float g0 = 0.5f * a + 0.5f * aadp;
    float g1 = w1 * a + (1.f - w1) * f;
    float g2 = w2 * a + (1.f - w2) * dd;
    G[0 * 1000000 + n * 1000 + m] = f2bf(g0);
    G[1 * 1000000 + n * 1000 + m] = f2bf(g1);
    G[2 * 1000000 + n * 1000 + m] = f2bf(g2);
    s0 += g0; s1 += g1; s2 += g2;
  }
  red[tid] = s0; __syncthreads();
  for (int st = 128; st > 0; st >>= 1) { if (tid < st) red[tid] += red[tid + st]; __syncthreads(); }
  if (tid == 0) rowsums[n] = red[0];
  __syncthreads();
  red[tid] = s1; __syncthreads();
  for (int st = 128; st > 0; st >>= 1) { if (tid < st) red[tid] += red[tid + st]; __syncthreads(); }
  if (tid == 0) rowsums[1000 + n] = red[0];
  __syncthreads();
  red[tid] = s2; __syncthreads();
  for (int st = 128; st > 0; st >>= 1) { if (tid < st) red[tid] += red[tid + st]; __syncthreads(); }
  if (tid == 0) rowsums[2000 + n] = red[0];
}

// sc[k] = mean_n( sum_a tanh(P[k,n,a]+fus_b[a]) * fus_v[a] )
__launch_bounds__(256)
__global__ void k_sc(const float* __restrict__ P, const float* fus_b, const float* fus_v, float* sc)
{
  __shared__ float red[256];
  const int k = blockIdx.x, tid = threadIdx.x;
  float local = 0;
  for (int n = tid; n < 1000; n += 256) {
    const float* p = P + (size_t)(k * 1000 + n) * 32;
    float s = 0;
#pragma unroll
    for (int a = 0; a < 32; a++) s += tanhf(p[a] + fus_b[a]) * fus_v[a];
    local += s;
  }
  red[tid] = local; __syncthreads();
  for (int st = 128; st > 0; st >>= 1) { if (tid < st) red[tid] += red[tid + st]; __syncthreads(); }
  if (tid == 0) sc[k] = red[0] * (1.f / 1000.f);
}

__launch_bounds__(256)
__global__ void k_alpha(const float* sc, const float* rowsums, float* alpha_out, float* dinv)
{
  __shared__ float al[3];
  const int tid = threadIdx.x;
  if (tid == 0) {
    float m = fmaxf(sc[0], fmaxf(sc[1], sc[2]));
    float e0 = __expf(sc[0] - m), e1 = __expf(sc[1] - m), e2 = __expf(sc[2] - m);
    float inv = 1.f / (e0 + e1 + e2);
    al[0] = e0 * inv; al[1] = e1 * inv; al[2] = e2 * inv;
    alpha_out[0] = al[0]; alpha_out[1] = al[1]; alpha_out[2] = al[2];
  }
  __syncthreads();
  const float a0 = al[0], a1 = al[1], a2 = al[2];
  for (int n = tid; n < 1000; n += 256) {
    float d = a0 * rowsums[n] + a1 * rowsums[1000 + n] + a2 * rowsums[2000 + n] + 1.0f;
    dinv[n] = rsqrtf(fmaxf(d, 1e-12f));
  }
}

// S_hat -> Sbf with 1024 K-pad stride (pad cols zeroed)
__launch_bounds__(256)
__global__ void k_shat(const u16* __restrict__ G, const float* alpha, const float* dinv,
                       u16* __restrict__ S)
{
  int idx = blockIdx.x * 256 + threadIdx.x;
  if (idx >= 1024000) return;
  int i = idx >> 10, j = idx & 1023;
  u16 val = 0;
  if (j < 1000) {
    const float a0 = alpha[0], a1 = alpha[1], a2 = alpha[2];
    int g = i * 1000 + j;
    float mg = a0 * bf2f(G[g]) + a1 * bf2f(G[1000000 + g]) + a2 * bf2f(G[2000000 + g]);
    if (i == j) mg += 1.0f;
    val = f2bf(mg * dinv[i] * dinv[j]);
  }
  S[(size_t)i * 1024 + j] = val;
}

// In-place LN2 over 96 ch on g-layout buffer
__launch_bounds__(256)
__global__ void k_ln2g(u16* __restrict__ g, const float* __restrict__ b2,
                       const float* __restrict__ g2, const float* __restrict__ be2)
{
  const int i = blockIdx.x * 256 + threadIdx.x;
  if (i >= 384000) return;
  u16* row = g + (size_t)i * 96;

  uint4 raw[12];
#pragma unroll
  for (int t = 0; t < 12; t++) raw[t] = *(const uint4*)((const u16*)row + t * 8);

  float s = 0, ss = 0;
#pragma unroll
  for (int t = 0; t < 12; t++) {
    const u16* ch = (const u16*)&raw[t];
#pragma unroll
    for (int e = 0; e < 8; e++) {
      float v = bf2f(ch[e]) + b2[t * 8 + e];
      s += v; ss += v * v;
    }
  }
  const float mean = s * (1.f / 96.f);
  const float var  = ss * (1.f / 96.f) - mean * mean;
  const float isd  = rsqrtf(var + 1e-5f);

#pragma unroll
  for (int t = 0; t < 12; t++) {
    const u16* ch = (const u16*)&raw[t];
#pragma unroll
    for (int p = 0; p < 2; p++) {
      int c0 = t * 8 + p * 4;
      u32 w0 = f2bf((bf2f(ch[p * 4 + 0]) + b2[c0 + 0] - mean) * isd * g2[c0 + 0] + be2[c0 + 0]);
      u32 w1 = f2bf((bf2f(ch[p * 4 + 1]) + b2[c0 + 1] - mean) * isd * g2[c0 + 1] + be2[c0 + 1]);
      u32 w2 = f2bf((bf2f(ch[p * 4 + 2]) + b2[c0 + 2] - mean) * isd * g2[c0 + 2] + be2[c0 + 2]);
      u32 w3 = f2bf((bf2f(ch[p * 4 + 3]) + b2[c0 + 3] - mean) * isd * g2[c0 + 3] + be2[c0 + 3]);
      ((u32*)row)[t * 4 + p * 2 + 0] = (w0 | (w1 << 16));
      ((u32*)row)[t * 4 + p * 2 + 1] = (w2 | (w3 << 16));
    }
  }
}

// ctx = Nv/L, split to hi/lo bf16, pack A' rows [ch | ch | cl] (K=576)
__launch_bounds__(256)
__global__ void k_ctxsplit(const float* __restrict__ Nv, const float* __restrict__ Lbuf,
                           u16* __restrict__ ctxs)
{
  const int i = blockIdx.x * 256 + threadIdx.x;
  if (i >= 32000 * 192) return;
  const int q = i / 192, c = i - q * 192;
  float v = Nv[i] / Lbuf[q];
  u16 hi = f2bf(v);
  u16 lo = f2bf(v - bf2f(hi));
  u16* row = ctxs + (size_t)q * 576;
  row[c] = hi; row[192 + c] = hi; row[384 + c] = lo;
}

// fc2: LDS-staged tiny GEMM + transposed store
__launch_bounds__(192)
__global__ void k_fc2(const float* __restrict__ hfc, const float* __restrict__ fc2W,
                      const float* __restrict__ fc2b, float* __restrict__ out)
{
  __shared__ float w2S[12][193];
  __shared__ float hS[16][193];
  const int tid = threadIdx.x;
  const int q0 = blockIdx.x * 16;
  for (int idx = tid; idx < 12 * 192; idx += 192) {
    int o = idx / 192, k = idx - o * 192;
    w2S[o][k] = fc2W[idx];
  }
  for (int idx = tid; idx < 16 * 192; idx += 192) {
    int qq = idx / 192, k = idx - qq * 192;
    hS[qq][k] = hfc[(size_t)(q0 + qq) * 192 + k];
  }
  __syncthreads();
  const int qq = tid / 12, o = tid - qq * 12;
  float acc = fc2b[o];
#pragma unroll 8
  for (int k = 0; k < 192; k++) acc += hS[qq][k] * w2S[o][k];
  const int q = q0 + qq;
  const int b = q / 1000, node = q - b * 1000;
  out[(size_t)b * 12000 + o * 1000 + node] = acc;
}

// ============================================================
extern "C" void kernel_launch(void* const* d_in, const int* in_sizes, int n_in,
                              void* d_out, int out_size, void* d_ws, size_t ws_size,
                              hipStream_t stream)
{
  const float* x     = (const float*)d_in[0];
  const float* A     = (const float*)d_in[1];
  const float* FSP   = (const float*)d_in[2];
  const float* DSP   = (const float*)d_in[3];
  const float* E1    = (const float*)d_in[4];
  const float* E2    = (const float*)d_in[5];
  const float* fus_W = (const float*)d_in[6];
  const float* fus_b = (const float*)d_in[7];
  const float* fus_v = (const float*)d_in[8];
  const float* beta1 = (const float*)d_in[9];
  const float* beta2 = (const float*)d_in[10];
  const float* gcn_W1= (const float*)d_in[11];
  const float* gcn_b1= (const float*)d_in[12];
  const float* ln1g  = (const float*)d_in[13];
  const float* ln1b  = (const float*)d_in[14];
  const float* gcn_W2= (const float*)d_in[15];
  const float* gcn_b2= (const float*)d_in[16];
  const float* ln2g  = (const float*)d_in[17];
  const float* ln2b  = (const float*)d_in[18];
  const float* Wih0  = (const float*)d_in[19];
  const float* Whh0  = (const float*)d_in[20];
  const float* bih0  = (const float*)d_in[21];
  const float* bhh0  = (const float*)d_in[22];
  const float* Wih1  = (const float*)d_in[23];
  const float* Whh1  = (const float*)d_in[24];
  const float* bih1  = (const float*)d_in[25];
  const float* bhh1  = (const float*)d_in[26];
  const float* att_w = (const float*)d_in[27];
  const float* fc1W  = (const float*)d_in[28];
  const float* fc1b  = (const float*)d_in[29];
  const float* fc2W  = (const float*)d_in[30];
  const float* fc2b  = (const float*)d_in[31];
  float* out = (float*)d_out;

  char* w = (char*)d_ws;
  auto alloc = [&](size_t bytes) -> char* {
    char* p = w;
    w += (bytes + 255) & ~(size_t)255;
    return p;
  };

  float* consts  = (float*)alloc(8 * 4);
  float* scp     = (float*)alloc(3 * 4);
  float* alphap  = (float*)alloc(3 * 4);
  float* rowsums = (float*)alloc(3000 * 4);
  float* dinvp   = (float*)alloc(1000 * 4);
  u16*   Gbuf    = (u16*)alloc((size_t)3000000 * 2);
  u16*   Sbf     = (u16*)alloc((size_t)1024 * 1024 * 2);
  u16*   xbf     = (u16*)alloc((size_t)384000 * 2);
  u16*   fusWbf  = (u16*)alloc((size_t)32000 * 2);
  u16*   Wih0b   = (u16*)alloc((size_t)55296 * 2);
  u16*   Whh0b   = (u16*)alloc((size_t)110592 * 2);
  u16*   Wih1b   = (u16*)alloc((size_t)110592 * 2);
  u16*   Whh1b   = (u16*)alloc((size_t)110592 * 2);
  u16*   w1s     = (u16*)alloc((size_t)192 * 576 * 2);
  u16*   W2s     = (u16*)alloc((size_t)96 * 192 * 2);
  float4* cwpk   = (float4*)alloc((size_t)96 * 16);
  float* Pbuf    = (float*)alloc((size_t)96000 * 4);
  float* yt      = (float*)alloc((size_t)384000 * 4);
  u16*   h2t     = (u16*)alloc((size_t)36864 * 1024 * 2);  // 75.5 MB; states/FC alias later
  u16*   Gg      = (u16*)alloc((size_t)36864000 * 2);      // 73.7 MB
  float* Nv      = (float*)alloc((size_t)6144000 * 4);
  float* Mbuf    = (float*)alloc((size_t)32000 * 4);
  float* Lbuf    = (float*)alloc((size_t)32000 * 4);
  float* score   = (float*)alloc((size_t)32000 * 4);

  // GRU state double-buffers alias the h2t region (dead after k_bigemm)
  u16* h0buf[2] = { h2t,                    h2t + (size_t)6144000 };
  u16* h1buf[2] = { h2t + (size_t)12288000, h2t + (size_t)18432000 };
  // FC-head aliases (states dead after GRU loop)
  u16*   ctxs = h2t;
  float* hfc  = (float*)(h2t + (size_t)18432000);

  k_prep<<<3174, 256, 0, stream>>>(x, fus_W, Wih0, Whh0, Wih1, Whh1, gcn_W1, gcn_b1,
                                   gcn_W2, ln1g, ln1b,
                                   xbf, fusWbf, Wih0b, Whh0b, Wih1b, Whh1b, W2s, cwpk, consts);
  k_w1split<<<144, 256, 0, stream>>>(fc1W, w1s);
  k_zero<<<557, 256, 0, stream>>>(h2t, score);
  k_adjrow<<<1000, 256, 0, stream>>>(A, FSP, DSP, E1, E2, beta1, beta2, Gbuf, rowsums);
  gemm_nt<0><<<dim3(1, 24), 256, 0, stream>>>(Gbuf, 1000, fusWbf, 1000, Pbuf, 32, 3000, 32, 1000, nullptr);
  k_sc<<<3, 256, 0, stream>>>(Pbuf, fus_b, fus_v, scp);
  k_alpha<<<1, 256, 0, stream>>>(scp, rowsums, alphap, dinvp);
  k_shat<<<4000, 256, 0, stream>>>(Gbuf, alphap, dinvp, Sbf);
  // yt[m, r] = sum_n S[m,n] * x[r,n]
  gemm_nt<0><<<dim3(6, 8), 256, 0, stream>>>(Sbf, 1024, xbf, 1000, yt, 384, 1000, 384, 1000, nullptr);
  // h2t = Hln @ W2 (LN1 fused, LDS-transposed coalesced stores)
  k_h2gemm<<<3000, 256, 0, stream>>>(yt, cwpk, W2s, consts, h2t);
  // Gg = S @ h2t^T  (73.7 GFLOP)
  k_bigemm<<<2304, 256, 0, stream>>>(Sbf, h2t, Gg);
  k_ln2g<<<1500, 256, 0, stream>>>(Gg, gcn_b2, ln2g, ln2b);

  for (int t = 0; t < 12; ++t) {
    u16* h0in  = h0buf[t & 1];
    u16* h0out = h0buf[(t & 1) ^ 1];
    u16* h1in  = h1buf[t & 1];
    u16* h1out = h1buf[(t & 1) ^ 1];
    k_gru<96, false><<<dim3(6, 250), 256, 0, stream>>>(
        Gg + t * 96, 1152, Wih0b, h0in, Whh0b, bih0, bhh0, h0out, nullptr, nullptr, t == 0);
    k_gru<192, true><<<dim3(6, 250), 256, 0, stream>>>(
        h0out, 192, Wih1b, h1in, Whh1b, bih1, bhh1, h1out, att_w, score, t == 0);
    k_pool<<<4000, 256, 0, stream>>>(h1out, score, Mbuf, Lbuf, Nv, t == 0);
  }

  // FC head
  k_ctxsplit<<<24000, 256, 0, stream>>>(Nv, Lbuf, ctxs);
  gemm_nt<3><<<dim3(3, 250), 256, 0, stream>>>(ctxs, 576, w1s, 576, hfc, 192, 32000, 192, 576, fc1b);
  k_fc2<<<2000, 192, 0, stream>>>(hfc, fc2W, fc2b, out);
}